// Round 8
// baseline (540.091 us; speedup 1.0000x reference)
//
#include <hip/hip_runtime.h>

typedef unsigned short u16;
typedef short short8 __attribute__((ext_vector_type(8)));
typedef short short4v __attribute__((ext_vector_type(4)));
typedef float floatx4 __attribute__((ext_vector_type(4)));
typedef float floatx4v __attribute__((ext_vector_type(4)));

#define SQ 2048
#define NH 16
#define HD 128
#define RD 64
#define NB 2
#define LDKV 5120
#define LDQ 3072

// padded LDS strides (odd multiples of 8 u16 = 16 B)
#define LKC 136
#define LKR 72
#define LVT 72
#define LP  72

__device__ __forceinline__ float bf2f(u16 u) {
  union { unsigned u; float f; } v; v.u = ((unsigned)u) << 16; return v.f;
}
__device__ __forceinline__ u16 f2bf(float f) {
  union { float f; unsigned u; } v; v.f = f;
  return (u16)((v.u + 0x7FFFu + ((v.u >> 16) & 1u)) >> 16);
}
__device__ __forceinline__ void gll16(const u16* g, u16* l) {
  __builtin_amdgcn_global_load_lds((const __attribute__((address_space(1))) void*)g,
                                   (__attribute__((address_space(3))) void*)l, 16, 0, 0);
}

// ---- x (f32) -> bf16, vectorized ----
__global__ __launch_bounds__(256) void convert_x(const float* __restrict__ src,
                                                 u16* __restrict__ dst, int n4) {
  const int i = blockIdx.x * 256 + threadIdx.x;
  if (i >= n4) return;
  const floatx4v v = *(const floatx4v*)(src + 4 * (size_t)i);
  short4v o;
  o.x = (short)f2bf(v.x); o.y = (short)f2bf(v.y);
  o.z = (short)f2bf(v.z); o.w = (short)f2bf(v.w);
  *(short4v*)(dst + 4 * (size_t)i) = o;
}

// ---- all 8 biases (f32) -> concatenated bf16 slots ----
__global__ __launch_bounds__(256) void convert_biases(
    const float* b0, const float* b1, const float* b2, const float* b3,
    const float* b4, const float* b5, const float* b6, const float* b7,
    u16* __restrict__ bc) {
  const int i = blockIdx.x * 256 + threadIdx.x;
  if (i >= 12288) return;
  float v;
  if      (i < 512)   v = b0[i];          // kvdb
  else if (i < 2048)  v = b1[i - 512];    // qdb
  else if (i < 4096)  v = b2[i - 2048];   // kub
  else if (i < 6144)  v = b3[i - 4096];   // vub
  else if (i < 7168)  v = b4[i - 6144];   // krb
  else if (i < 9216)  v = b5[i - 7168];   // qub
  else if (i < 10240) v = b6[i - 9216];   // qrb
  else                v = b7[i - 10240];  // ob
  bc[i] = f2bf(v);
}

// ---- weight transpose: in[R][C] f32 -> out[C][R] bf16 ----
__global__ __launch_bounds__(256) void transpose_w(const float* __restrict__ in,
                                                   u16* __restrict__ out,
                                                   int R, int C) {
  __shared__ u16 tile[32][33];
  const int c0 = blockIdx.x * 32, r0 = blockIdx.y * 32;
  const int x = threadIdx.x & 31, y = threadIdx.x >> 5;
#pragma unroll
  for (int i = 0; i < 32; i += 8)
    tile[y + i][x] = f2bf(in[(size_t)(r0 + y + i) * C + c0 + x]);
  __syncthreads();
#pragma unroll
  for (int i = 0; i < 32; i += 8)
    out[(size_t)(c0 + y + i) * R + r0 + x] = tile[x][y + i];
}

// ---- V (cols 2048..4095 of KV [4096,5120]) -> Vt [B,H,HD,S] ----
__global__ __launch_bounds__(256) void transpose_v(const u16* __restrict__ KV,
                                                   u16* __restrict__ Vt) {
  __shared__ u16 tile[32][33];
  const int bh = blockIdx.z, b = bh >> 4, hh = bh & 15;
  const u16* pin = KV + (size_t)b * SQ * LDKV + 2048 + (size_t)hh * HD;
  u16* pout = Vt + (size_t)bh * HD * SQ;
  const int s0 = blockIdx.x * 32, d0 = blockIdx.y * 32;
  const int x = threadIdx.x & 31, y = threadIdx.x >> 5;
#pragma unroll
  for (int i = 0; i < 32; i += 8)
    tile[y + i][x] = pin[(size_t)(s0 + y + i) * LDKV + d0 + x];
  __syncthreads();
#pragma unroll
  for (int i = 0; i < 32; i += 8)
    pout[(size_t)(d0 + y + i) * SQ + s0 + x] = tile[x][y + i];
}

// ---- RoPE in place on a [4096 x (16*64)] submatrix at col `coloff`, ld `ld` ----
__global__ __launch_bounds__(256) void rope_inplace(u16* __restrict__ buf,
                                                    int ld, int coloff) {
  const int i = blockIdx.x * 256 + threadIdx.x;
  if (i >= NB * SQ * NH * 32) return;
  const int j = i & 31;
  const int hh = (i >> 5) & 15;
  const int row = i >> 9;
  const int s = row & (SQ - 1);
  u16* p = buf + (size_t)row * ld + coloff + hh * RD + 2 * j;
  const float x1 = bf2f(p[0]), x2 = bf2f(p[1]);
  const float inv = exp2f(-(float)j * 0.41524101186092031f);  // 10000^(-j/32)
  const float ang = (float)s * inv;
  float sn, cs;
  sincosf(ang, &sn, &cs);
  p[0] = f2bf(x1 * cs - x2 * sn);
  p[1] = f2bf(x1 * sn + x2 * cs);
}

// ---- C[M=4096,N] = A[.,K](lda) * Bt[N,K]^T + bias; out bf16(ldc) or f32 ----
// r8: 128x64 tile, 256 thr / 4 waves (2Mx2N, per-wave 64x32, acc[4][2]).
// r7 post-mortem: waves added WITHIN a block are barrier-locksteped — they
// don't hide the per-step vmcnt(0) drain. Independent-blocks-per-CU is the
// lever (m97 @4 blocks/CU = 912 TF vs m102 @1 = 320). Halving BN doubles the
// grid: G1/G4 512->1024 blocks (4/CU), G2 ->2560 (10/CU), G3 ->1536 (6/CU).
// BK=64 split K-half buffers kept (r4 win); linear gll16 dests (rule #21);
// per-output MFMA accumulation order unchanged -> numerics identical.
// LDS 24 KB/block; VGPR ~80 < 128 cap at (256,4).
__global__ __launch_bounds__(256, 4) void gemm_bt(const u16* __restrict__ A, int lda,
                                                  const u16* __restrict__ Bt,
                                                  const u16* __restrict__ bias,
                                                  void* __restrict__ Cout, int ldc,
                                                  int wf32, int N, int K) {
  __shared__ __align__(16) u16 lAk0[128 * 32];
  __shared__ __align__(16) u16 lAk1[128 * 32];
  __shared__ __align__(16) u16 lBk0[64 * 32];
  __shared__ __align__(16) u16 lBk1[64 * 32];
  const int t = threadIdx.x;
  const int lane = t & 63, w = t >> 6;      // 4 waves
  const int wm = w & 1, wn = w >> 1;        // 2 M-halves x 2 N-halves
  const int m0 = blockIdx.y * 128, n0 = blockIdx.x * 64;
  const int srow = t >> 2, scol = (t & 3) * 8;  // 256 thr cover [64][32] once
  const u16* gA = A + (size_t)(m0 + srow) * lda + scol;
  const u16* gB = Bt + (size_t)(n0 + srow) * K + scol;
  const int lane_m = lane & 15, lane_k = (lane >> 4) * 8;
  floatx4 acc[4][2] = {};
  for (int k0 = 0; k0 < K; k0 += 64) {
    // K-half 0
    gll16(gA + k0, lAk0 + (16 * w) * 32);                          // A rows 0-63
    gll16(gA + (size_t)64 * lda + k0, lAk0 + (64 + 16 * w) * 32);  // A rows 64-127
    gll16(gB + k0, lBk0 + (16 * w) * 32);                          // B rows 0-63
    // K-half 1
    gll16(gA + k0 + 32, lAk1 + (16 * w) * 32);
    gll16(gA + (size_t)64 * lda + k0 + 32, lAk1 + (64 + 16 * w) * 32);
    gll16(gB + k0 + 32, lBk1 + (16 * w) * 32);
    __syncthreads();
    {
      short8 af[4], bf[2];
#pragma unroll
      for (int i = 0; i < 4; i++)
        af[i] = *(const short8*)(lAk0 + (wm * 64 + i * 16 + lane_m) * 32 + lane_k);
#pragma unroll
      for (int i = 0; i < 2; i++)
        bf[i] = *(const short8*)(lBk0 + (wn * 32 + i * 16 + lane_m) * 32 + lane_k);
#pragma unroll
      for (int mi = 0; mi < 4; mi++)
#pragma unroll
        for (int ni = 0; ni < 2; ni++)
          acc[mi][ni] = __builtin_amdgcn_mfma_f32_16x16x32_bf16(af[mi], bf[ni], acc[mi][ni], 0, 0, 0);
    }
    {
      short8 af[4], bf[2];
#pragma unroll
      for (int i = 0; i < 4; i++)
        af[i] = *(const short8*)(lAk1 + (wm * 64 + i * 16 + lane_m) * 32 + lane_k);
#pragma unroll
      for (int i = 0; i < 2; i++)
        bf[i] = *(const short8*)(lBk1 + (wn * 32 + i * 16 + lane_m) * 32 + lane_k);
#pragma unroll
      for (int mi = 0; mi < 4; mi++)
#pragma unroll
        for (int ni = 0; ni < 2; ni++)
          acc[mi][ni] = __builtin_amdgcn_mfma_f32_16x16x32_bf16(af[mi], bf[ni], acc[mi][ni], 0, 0, 0);
    }
    __syncthreads();
  }
  const int quad = lane >> 4;
#pragma unroll
  for (int ni = 0; ni < 2; ni++) {
    const int col = n0 + wn * 32 + ni * 16 + lane_m;
    const float bv = bf2f(bias[col]);
#pragma unroll
    for (int mi = 0; mi < 4; mi++) {
      const int row = m0 + wm * 64 + mi * 16 + quad * 4;
      if (wf32) {
        float* pc = (float*)Cout + (size_t)row * ldc + col;
#pragma unroll
        for (int r = 0; r < 4; r++)
          pc[(size_t)r * ldc] = acc[mi][ni][r] + bv;
      } else {
        u16* pc = (u16*)Cout + (size_t)row * ldc + col;
#pragma unroll
        for (int r = 0; r < 4; r++)
          pc[(size_t)r * ldc] = f2bf(acc[mi][ni][r] + bv);
      }
    }
  }
}

// ---- flash attention: grid (16, 32); 8 waves, 128 q-rows/block, 64-key tiles ----
// Verified r5-r7 structure (157 us): reg-staged 1-deep prefetch, setprio around
// MFMA clusters, T13 defer-max. Untouched for clean attribution.
__global__ __launch_bounds__(512, 4) void flash_attn(const u16* __restrict__ Q,
                                                     const u16* __restrict__ KV,
                                                     const u16* __restrict__ Vt,
                                                     u16* __restrict__ Ctx) {
  __shared__ __align__(16) u16 lKc[64 * LKC];
  __shared__ __align__(16) u16 lKr[64 * LKR];
  __shared__ __align__(16) u16 lVt[128 * LVT];
  __shared__ __align__(16) u16 lP[8 * 16 * LP];
  const int t = threadIdx.x, lane = t & 63, w = t >> 6;
  const int col = blockIdx.y;
  const int qtile = (col < 16) ? (15 - (int)blockIdx.x) : (int)blockIdx.x;
  const int h = col & (NH - 1);
  const int b = col >> 4;
  const int q0 = qtile * 128;
  const int nkt = 2 * qtile + 2;
  const int lane_m = lane & 15, quad = lane >> 4, lane_k = quad * 8;

  // Q fragments (A-operand), one 16-row stripe per wave
  const int qrow = q0 + 16 * w + lane_m;
  const u16* qcp = Q + (size_t)(b * SQ + qrow) * LDQ + h * HD;
  const u16* qrp = Q + (size_t)(b * SQ + qrow) * LDQ + 2048 + h * RD;
  short8 qfc[4], qfr[2];
#pragma unroll
  for (int ks = 0; ks < 4; ks++) qfc[ks] = *(const short8*)(qcp + ks * 32 + lane_k);
#pragma unroll
  for (int ks = 0; ks < 2; ks++) qfr[ks] = *(const short8*)(qrp + ks * 32 + lane_k);

  floatx4 O[8] = {};
  float mrow[4], lsum[4];
#pragma unroll
  for (int r = 0; r < 4; r++) { mrow[r] = -1e30f; lsum[r] = 0.f; }

  const u16* gKc = KV + (size_t)b * SQ * LDKV + h * HD;          // + key*LDKV + d
  const u16* gKr = KV + (size_t)b * SQ * LDKV + 4096 + h * RD;   // + key*LDKV + d
  const u16* gVt = Vt + (size_t)(b * NH + h) * HD * SQ;          // + d*SQ + key
  const float C2 = 0.10412825525540364f;  // (1/sqrt(192)) * log2(e)
  const float THR = 28.8f;                // defer-max threshold: exp2(THR*C2)=8

  // register staging (global -> reg prefetch -> LDS), 512 threads
  short8 rKc[2], rKr, rVt[2];
  auto load_tile = [&](int kb) {
#pragma unroll
    for (int i = 0; i < 2; i++) {
      const int c = t + i * 512, row = c >> 4, cc = (c & 15) * 8;
      rKc[i] = *(const short8*)(gKc + (size_t)(kb + row) * LDKV + cc);
    }
    {
      const int row = t >> 3, cc = (t & 7) * 8;
      rKr = *(const short8*)(gKr + (size_t)(kb + row) * LDKV + cc);
    }
#pragma unroll
    for (int i = 0; i < 2; i++) {
      const int c = t + i * 512, row = c >> 3, cc = (c & 7) * 8;
      rVt[i] = *(const short8*)(gVt + (size_t)row * SQ + kb + cc);
    }
  };

  const int wrow_lo = q0 + 16 * w;
  const int wrow_hi = wrow_lo + 15;

  load_tile(0);
  for (int kt = 0; kt < nkt; kt++) {
    const int kb = kt * 64;
    __syncthreads();  // previous tile's LDS reads complete
#pragma unroll
    for (int i = 0; i < 2; i++) {
      const int c = t + i * 512, row = c >> 4, cc = (c & 15) * 8;
      *(short8*)(lKc + row * LKC + cc) = rKc[i];
    }
    {
      const int row = t >> 3, cc = (t & 7) * 8;
      *(short8*)(lKr + row * LKR + cc) = rKr;
    }
#pragma unroll
    for (int i = 0; i < 2; i++) {
      const int c = t + i * 512, row = c >> 3, cc = (c & 7) * 8;
      *(short8*)(lVt + row * LVT + cc) = rVt[i];
    }
    __syncthreads();
    if (kt < nkt - 1) load_tile(kb + 64);  // prefetch overlaps compute below

    if (kb <= wrow_hi) {  // wave-level skip of fully-masked tiles (barriers stay uniform)
      float ss[4][4];
      __builtin_amdgcn_s_setprio(1);
#pragma unroll
      for (int n = 0; n < 4; n++) {
        floatx4 a = {0.f, 0.f, 0.f, 0.f};
#pragma unroll
        for (int ks = 0; ks < 4; ks++) {
          const short8 kf = *(const short8*)(lKc + (n * 16 + lane_m) * LKC + ks * 32 + lane_k);
          a = __builtin_amdgcn_mfma_f32_16x16x32_bf16(qfc[ks], kf, a, 0, 0, 0);
        }
#pragma unroll
        for (int ks = 0; ks < 2; ks++) {
          const short8 kf = *(const short8*)(lKr + (n * 16 + lane_m) * LKR + ks * 32 + lane_k);
          a = __builtin_amdgcn_mfma_f32_16x16x32_bf16(qfr[ks], kf, a, 0, 0, 0);
        }
#pragma unroll
        for (int r = 0; r < 4; r++) ss[n][r] = a[r];
      }
      __builtin_amdgcn_s_setprio(0);
      if (kb + 63 > wrow_lo) {  // causal mask (partial tiles)
#pragma unroll
        for (int n = 0; n < 4; n++) {
          const int kcol = kb + n * 16 + lane_m;
#pragma unroll
          for (int r = 0; r < 4; r++) {
            const int row = wrow_lo + quad * 4 + r;
            if (kcol > row) ss[n][r] = -1e30f;
          }
        }
      }
      // per-row tile max
      float mt[4];
#pragma unroll
      for (int r = 0; r < 4; r++) {
        float m = fmaxf(fmaxf(ss[0][r], ss[1][r]), fmaxf(ss[2][r], ss[3][r]));
#pragma unroll
        for (int d = 1; d < 16; d <<= 1) m = fmaxf(m, __shfl_xor(m, d));
        mt[r] = m;
      }
      // T13 defer-max: rescale only if some row grew past THR
      const bool grow = (mt[0] > mrow[0] + THR) || (mt[1] > mrow[1] + THR) ||
                        (mt[2] > mrow[2] + THR) || (mt[3] > mrow[3] + THR);
      if (__any(grow)) {
#pragma unroll
        for (int r = 0; r < 4; r++) {
          const float mn = fmaxf(mrow[r], mt[r]);
          const float alpha = exp2f((mrow[r] - mn) * C2);
          mrow[r] = mn;
          lsum[r] *= alpha;
#pragma unroll
          for (int vb = 0; vb < 8; vb++) O[vb][r] *= alpha;
        }
      }
      float pw[4][4];
#pragma unroll
      for (int r = 0; r < 4; r++) {
        float s = 0.f;
#pragma unroll
        for (int n = 0; n < 4; n++) {
          const float p = exp2f((ss[n][r] - mrow[r]) * C2);
          pw[n][r] = p;
          s += p;
        }
#pragma unroll
        for (int d = 1; d < 16; d <<= 1) s += __shfl_xor(s, d);
        lsum[r] += s;
      }
      // P: C-layout -> LDS (per-wave region) -> A-layout
#pragma unroll
      for (int n = 0; n < 4; n++)
#pragma unroll
        for (int r = 0; r < 4; r++)
          lP[(w * 16 + quad * 4 + r) * LP + n * 16 + lane_m] = f2bf(pw[n][r]);
      asm volatile("s_waitcnt lgkmcnt(0)" ::: "memory");
      __builtin_amdgcn_s_setprio(1);
#pragma unroll
      for (int ks = 0; ks < 2; ks++) {
        const short8 pf = *(const short8*)(lP + (w * 16 + lane_m) * LP + ks * 32 + lane_k);
#pragma unroll
        for (int vb = 0; vb < 8; vb++) {
          const short8 vf = *(const short8*)(lVt + (vb * 16 + lane_m) * LVT + ks * 32 + lane_k);
          O[vb] = __builtin_amdgcn_mfma_f32_16x16x32_bf16(pf, vf, O[vb], 0, 0, 0);
        }
      }
      __builtin_amdgcn_s_setprio(0);
    }
  }
  float inv[4];
#pragma unroll
  for (int r = 0; r < 4; r++) inv[r] = 1.f / lsum[r];
#pragma unroll
  for (int vb = 0; vb < 8; vb++) {
#pragma unroll
    for (int r = 0; r < 4; r++) {
      const int row = wrow_lo + quad * 4 + r;
      Ctx[(size_t)(b * SQ + row) * 2048 + h * HD + vb * 16 + lane_m] = f2bf(O[vb][r] * inv[r]);
    }
  }
}

extern "C" void kernel_launch(void* const* d_in, const int* in_sizes, int n_in,
                              void* d_out, int out_size, void* d_ws, size_t ws_size,
                              hipStream_t stream) {
  (void)in_sizes; (void)n_in; (void)out_size; (void)ws_size;
  const float* x    = (const float*)d_in[0];
  const float* kvdw = (const float*)d_in[2];
  const float* kvdb = (const float*)d_in[3];
  const float* kuw  = (const float*)d_in[4];
  const float* kub  = (const float*)d_in[5];
  const float* vuw  = (const float*)d_in[6];
  const float* vub  = (const float*)d_in[7];
  const float* krw  = (const float*)d_in[8];
  const float* krb  = (const float*)d_in[9];
  const float* qdw  = (const float*)d_in[10];
  const float* qdb  = (const float*)d_in[11];
  const float* quw  = (const float*)d_in[12];
  const float* qub  = (const float*)d_in[13];
  const float* qrw  = (const float*)d_in[14];
  const float* qrb  = (const float*)d_in[15];
  const float* ow   = (const float*)d_in[16];
  const float* ob   = (const float*)d_in[17];

  // workspace layout (u16 units), ~115 MB, lifetime-aliased
  u16* p = (u16*)d_ws;
  u16* bc   = p;  p += 16384;
  u16* WT1  = p;  p += (size_t)2048 * 2048;  // kvd^T | qd^T   [2048,2048]
  u16* WT2  = p;  p += (size_t)5120 * 512;   // ku^T|vu^T|kr^T [5120,512]
  u16* WT3  = p;  p += (size_t)3072 * 1536;  // qu^T|qr^T      [3072,1536]
  u16* Ctx  = WT1;                           // overlays WT1..WT3 (dead by flash)
  u16* WTo  = p;  p += (size_t)2048 * 2048;  // o^T            [2048,2048]
  u16* KVQd = p;  p += (size_t)4096 * 2048;  // kv_c|q_c       [4096,2048]
  u16* Vt   = KVQd;                          // overlays (dead after G3)
  u16* KV   = p;  p += (size_t)4096 * 5120;  // Kc|V|Kr        [4096,5120]
  u16* Qb   = p;  p += (size_t)4096 * 3072;  // Qc|Qr          [4096,3072]
  u16* xc   = Qb;                            // overlays Q (dead after G1)

  convert_x<<<dim3(8192), 256, 0, stream>>>(x, xc, 4096 * 2048 / 4);
  convert_biases<<<dim3(48), 256, 0, stream>>>(kvdb, qdb, kub, vub, krb, qub, qrb, ob, bc);

  auto T = [&](const float* in, u16* out, int R, int C) {
    transpose_w<<<dim3(C / 32, R / 32), 256, 0, stream>>>(in, out, R, C);
  };
  T(kvdw, WT1, 2048, 512);
  T(qdw,  WT1 + (size_t)512 * 2048, 2048, 1536);
  T(kuw,  WT2, 512, 2048);
  T(vuw,  WT2 + (size_t)2048 * 512, 512, 2048);
  T(krw,  WT2 + (size_t)4096 * 512, 512, 1024);
  T(quw,  WT3, 1536, 2048);
  T(qrw,  WT3 + (size_t)2048 * 1536, 1536, 1024);
  T(ow,   WTo, 2048, 2048);

  auto G = [&](const u16* A, int lda, const u16* Bt, const u16* bias,
               void* Cout, int ldc, int wf32, int N, int K) {
    gemm_bt<<<dim3(N / 64, 4096 / 128), 256, 0, stream>>>(A, lda, Bt, bias, Cout, ldc, wf32, N, K);
  };
  G(xc, 2048, WT1, bc, KVQd, 2048, 0, 2048, 2048);                 // kv_c | q_c
  G(KVQd, 2048, WT2, bc + 2048, KV, LDKV, 0, 5120, 512);           // Kc | V | Kr
  G(KVQd + 512, 2048, WT3, bc + 7168, Qb, LDQ, 0, 3072, 1536);     // Qc | Qr

  rope_inplace<<<dim3((NB * SQ * NH * 32) / 256), 256, 0, stream>>>(KV, LDKV, 4096);
  rope_inplace<<<dim3((NB * SQ * NH * 32) / 256), 256, 0, stream>>>(Qb, LDQ, 2048);
  transpose_v<<<dim3(SQ / 32, HD / 32, NB * NH), 256, 0, stream>>>(KV, Vt);
  flash_attn<<<dim3(16, 32), 512, 0, stream>>>(Qb, KV, Vt, Ctx);

  G(Ctx, 2048, WTo, bc + 10240, d_out, 2048, 1, 2048, 2048);       // out proj (f32)
}

// Round 9
// 505.180 us; speedup vs baseline: 1.0691x; 1.0691x over previous
//
#include <hip/hip_runtime.h>

typedef unsigned short u16;
typedef short short8 __attribute__((ext_vector_type(8)));
typedef short short4v __attribute__((ext_vector_type(4)));
typedef float floatx4 __attribute__((ext_vector_type(4)));
typedef float floatx4v __attribute__((ext_vector_type(4)));

#define SQ 2048
#define NH 16
#define HD 128
#define RD 64
#define NB 2
#define LDKV 5120
#define LDQ 3072

// padded LDS strides (odd multiples of 8 u16 = 16 B)
#define LKC 136
#define LKR 72
#define LVT 72
#define LP  72

// workspace offsets (u16 units) — shared by host launcher and merged kernels
#define OFF_BC   ((size_t)0)
#define OFF_WT1  ((size_t)16384)
#define OFF_WT2  (OFF_WT1 + (size_t)2048 * 2048)
#define OFF_WT3  (OFF_WT2 + (size_t)5120 * 512)
#define OFF_WTO  (OFF_WT3 + (size_t)3072 * 1536)
#define OFF_KVQD (OFF_WTO + (size_t)2048 * 2048)
#define OFF_KV   (OFF_KVQD + (size_t)4096 * 2048)
#define OFF_QB   (OFF_KV + (size_t)4096 * 5120)

__device__ __forceinline__ float bf2f(u16 u) {
  union { unsigned u; float f; } v; v.u = ((unsigned)u) << 16; return v.f;
}
__device__ __forceinline__ u16 f2bf(float f) {
  union { float f; unsigned u; } v; v.f = f;
  return (u16)((v.u + 0x7FFFu + ((v.u >> 16) & 1u)) >> 16);
}
__device__ __forceinline__ void gll16(const u16* g, u16* l) {
  __builtin_amdgcn_global_load_lds((const __attribute__((address_space(1))) void*)g,
                                   (__attribute__((address_space(3))) void*)l, 16, 0, 0);
}

// ---- prep: ONE launch = convert_x + convert_biases + all 8 weight transposes.
// r9: launch-count reduction (18 -> 7 total). All ops independent, math and
// write targets bit-identical to the split kernels; only launch packing changed.
__global__ __launch_bounds__(256) void prep(
    const float* __restrict__ x,
    const float* b0, const float* b1, const float* b2, const float* b3,
    const float* b4, const float* b5, const float* b6, const float* b7,
    const float* w0, const float* w1, const float* w2, const float* w3,
    const float* w4, const float* w5, const float* w6, const float* w7,
    u16* __restrict__ ws) {
  __shared__ u16 tile[32][33];
  const int blk = blockIdx.x, t = threadIdx.x;

  if (blk < 8192) {  // convert_x: x f32 -> bf16 at xc (= Qb overlay)
    const int i = blk * 256 + t;  // exactly 4096*2048/4 threads
    const floatx4v v = *(const floatx4v*)(x + 4 * (size_t)i);
    short4v o;
    o.x = (short)f2bf(v.x); o.y = (short)f2bf(v.y);
    o.z = (short)f2bf(v.z); o.w = (short)f2bf(v.w);
    *(short4v*)(ws + OFF_QB + 4 * (size_t)i) = o;
    return;
  }
  if (blk < 8240) {  // biases -> bc
    const int i = (blk - 8192) * 256 + t;
    if (i >= 12288) return;
    float v;
    if      (i < 512)   v = b0[i];          // kvdb
    else if (i < 2048)  v = b1[i - 512];    // qdb
    else if (i < 4096)  v = b2[i - 2048];   // kub
    else if (i < 6144)  v = b3[i - 4096];   // vub
    else if (i < 7168)  v = b4[i - 6144];   // krb
    else if (i < 9216)  v = b5[i - 7168];   // qub
    else if (i < 10240) v = b6[i - 9216];   // qrb
    else                v = b7[i - 10240];  // ob
    ws[OFF_BC + i] = f2bf(v);
    return;
  }
  // weight transposes: in[R][C] f32 -> out[C][R] bf16
  const int f = blk - 8240;  // [0, 15360)
  const float* in; size_t oo; int R, C, start;
  if      (f < 1024)  { in = w0; oo = OFF_WT1;                        R = 2048; C = 512;  start = 0; }
  else if (f < 4096)  { in = w1; oo = OFF_WT1 + (size_t)512 * 2048;   R = 2048; C = 1536; start = 1024; }
  else if (f < 5120)  { in = w2; oo = OFF_WT2;                        R = 512;  C = 2048; start = 4096; }
  else if (f < 6144)  { in = w3; oo = OFF_WT2 + (size_t)2048 * 512;   R = 512;  C = 2048; start = 5120; }
  else if (f < 6656)  { in = w4; oo = OFF_WT2 + (size_t)4096 * 512;   R = 512;  C = 1024; start = 6144; }
  else if (f < 9728)  { in = w5; oo = OFF_WT3;                        R = 1536; C = 2048; start = 6656; }
  else if (f < 11264) { in = w6; oo = OFF_WT3 + (size_t)2048 * 1536;  R = 1536; C = 1024; start = 9728; }
  else                { in = w7; oo = OFF_WTO;                        R = 2048; C = 2048; start = 11264; }
  u16* out = ws + oo;
  const int local = f - start, nx = C / 32;
  const int c0 = (local % nx) * 32, r0 = (local / nx) * 32;
  const int xx = t & 31, y = t >> 5;
#pragma unroll
  for (int i = 0; i < 32; i += 8)
    tile[y + i][xx] = f2bf(in[(size_t)(r0 + y + i) * C + c0 + xx]);
  __syncthreads();
#pragma unroll
  for (int i = 0; i < 32; i += 8)
    out[(size_t)(c0 + y + i) * R + r0 + xx] = tile[xx][y + i];
}

// ---- post: ONE launch = rope(KV) + rope(Qb) + transpose_v.
// Disjoint regions: rope-KV writes KV cols 4096+, transpose_v reads KV cols
// 2048-4095, rope-Qb writes Qb cols 2048+ -> blocks may run in any order.
__global__ __launch_bounds__(256) void post(u16* __restrict__ ws) {
  __shared__ u16 tile[32][33];
  const int blk = blockIdx.x, t = threadIdx.x;

  if (blk < 16384) {  // rope in place (8192 blocks KV, 8192 Qb)
    u16* buf; int ld, coloff, f;
    if (blk < 8192) { buf = ws + OFF_KV; ld = LDKV; coloff = 4096; f = blk; }
    else            { buf = ws + OFF_QB; ld = LDQ;  coloff = 2048; f = blk - 8192; }
    const int i = f * 256 + t;  // exactly NB*SQ*NH*32 threads
    const int j = i & 31;
    const int hh = (i >> 5) & 15;
    const int row = i >> 9;
    const int s = row & (SQ - 1);
    u16* p = buf + (size_t)row * ld + coloff + hh * RD + 2 * j;
    const float x1 = bf2f(p[0]), x2 = bf2f(p[1]);
    const float inv = exp2f(-(float)j * 0.41524101186092031f);  // 10000^(-j/32)
    const float ang = (float)s * inv;
    float sn, cs;
    sincosf(ang, &sn, &cs);
    p[0] = f2bf(x1 * cs - x2 * sn);
    p[1] = f2bf(x1 * sn + x2 * cs);
    return;
  }
  // transpose_v: V (cols 2048..4095 of KV) -> Vt [B,H,HD,S] (= KVQd overlay)
  const int f = blk - 16384;            // [0, 8192)
  const int bh = f >> 8, rem = f & 255;
  const int b = bh >> 4, hh = bh & 15;
  const int s0 = (rem & 63) * 32, d0 = (rem >> 6) * 32;
  const u16* pin = ws + OFF_KV + (size_t)b * SQ * LDKV + 2048 + (size_t)hh * HD;
  u16* pout = ws + OFF_KVQD + (size_t)bh * HD * SQ;
  const int xx = t & 31, y = t >> 5;
#pragma unroll
  for (int i = 0; i < 32; i += 8)
    tile[y + i][xx] = pin[(size_t)(s0 + y + i) * LDKV + d0 + xx];
  __syncthreads();
#pragma unroll
  for (int i = 0; i < 32; i += 8)
    pout[(size_t)(d0 + y + i) * SQ + s0 + xx] = tile[xx][y + i];
}

// ---- C[M=4096,N] = A[.,K](lda) * Bt[N,K]^T + bias; out bf16(ldc) or f32 ----
// r7's exact kernel (best measured config, 523 us total): 8 waves / 512 thr per
// 128^2 tile, BK=64 split K-half buffers, linear gll16 dests (rule #21).
// r8's 128x64 tile REGRESSED (+17 us: 1.5x staged traffic); reverted.
__global__ __launch_bounds__(512, 4) void gemm_bt(const u16* __restrict__ A, int lda,
                                                  const u16* __restrict__ Bt,
                                                  const u16* __restrict__ bias,
                                                  void* __restrict__ Cout, int ldc,
                                                  int wf32, int N, int K) {
  __shared__ __align__(16) u16 lAk0[128 * 32];
  __shared__ __align__(16) u16 lAk1[128 * 32];
  __shared__ __align__(16) u16 lBk0[128 * 32];
  __shared__ __align__(16) u16 lBk1[128 * 32];
  const int t = threadIdx.x;
  const int lane = t & 63, w = t >> 6;      // 8 waves
  const int wm = w & 1, wn = w >> 1;        // 2 M-halves x 4 N-quarters
  const int m0 = blockIdx.y * 128, n0 = blockIdx.x * 128;
  const int srow = t >> 2, scol = (t & 3) * 8;  // 512 thr cover [128][32] once
  const u16* gA = A + (size_t)(m0 + srow) * lda + scol;
  const u16* gB = Bt + (size_t)(n0 + srow) * K + scol;
  u16* const ldA0 = lAk0 + (16 * w) * 32;   // wave-uniform gll16 dests
  u16* const ldA1 = lAk1 + (16 * w) * 32;
  u16* const ldB0 = lBk0 + (16 * w) * 32;
  u16* const ldB1 = lBk1 + (16 * w) * 32;
  const int lane_m = lane & 15, lane_k = (lane >> 4) * 8;
  floatx4 acc[4][2] = {};
  for (int k0 = 0; k0 < K; k0 += 64) {
    gll16(gA + k0, ldA0);
    gll16(gA + k0 + 32, ldA1);
    gll16(gB + k0, ldB0);
    gll16(gB + k0 + 32, ldB1);
    __syncthreads();
    {
      short8 af[4], bf[2];
#pragma unroll
      for (int i = 0; i < 4; i++)
        af[i] = *(const short8*)(lAk0 + (wm * 64 + i * 16 + lane_m) * 32 + lane_k);
#pragma unroll
      for (int i = 0; i < 2; i++)
        bf[i] = *(const short8*)(lBk0 + (wn * 32 + i * 16 + lane_m) * 32 + lane_k);
#pragma unroll
      for (int mi = 0; mi < 4; mi++)
#pragma unroll
        for (int ni = 0; ni < 2; ni++)
          acc[mi][ni] = __builtin_amdgcn_mfma_f32_16x16x32_bf16(af[mi], bf[ni], acc[mi][ni], 0, 0, 0);
    }
    {
      short8 af[4], bf[2];
#pragma unroll
      for (int i = 0; i < 4; i++)
        af[i] = *(const short8*)(lAk1 + (wm * 64 + i * 16 + lane_m) * 32 + lane_k);
#pragma unroll
      for (int i = 0; i < 2; i++)
        bf[i] = *(const short8*)(lBk1 + (wn * 32 + i * 16 + lane_m) * 32 + lane_k);
#pragma unroll
      for (int mi = 0; mi < 4; mi++)
#pragma unroll
        for (int ni = 0; ni < 2; ni++)
          acc[mi][ni] = __builtin_amdgcn_mfma_f32_16x16x32_bf16(af[mi], bf[ni], acc[mi][ni], 0, 0, 0);
    }
    __syncthreads();
  }
  const int quad = lane >> 4;
#pragma unroll
  for (int ni = 0; ni < 2; ni++) {
    const int col = n0 + wn * 32 + ni * 16 + lane_m;
    const float bv = bf2f(bias[col]);
#pragma unroll
    for (int mi = 0; mi < 4; mi++) {
      const int row = m0 + wm * 64 + mi * 16 + quad * 4;
      if (wf32) {
        float* pc = (float*)Cout + (size_t)row * ldc + col;
#pragma unroll
        for (int r = 0; r < 4; r++)
          pc[(size_t)r * ldc] = acc[mi][ni][r] + bv;
      } else {
        u16* pc = (u16*)Cout + (size_t)row * ldc + col;
#pragma unroll
        for (int r = 0; r < 4; r++)
          pc[(size_t)r * ldc] = f2bf(acc[mi][ni][r] + bv);
      }
    }
  }
}

// ---- flash attention: grid (16, 32); 8 waves, 128 q-rows/block, 64-key tiles ----
// Verified r5-r8 structure (156 us): reg-staged 1-deep prefetch, setprio around
// MFMA clusters, T13 defer-max. Untouched.
__global__ __launch_bounds__(512, 4) void flash_attn(const u16* __restrict__ Q,
                                                     const u16* __restrict__ KV,
                                                     const u16* __restrict__ Vt,
                                                     u16* __restrict__ Ctx) {
  __shared__ __align__(16) u16 lKc[64 * LKC];
  __shared__ __align__(16) u16 lKr[64 * LKR];
  __shared__ __align__(16) u16 lVt[128 * LVT];
  __shared__ __align__(16) u16 lP[8 * 16 * LP];
  const int t = threadIdx.x, lane = t & 63, w = t >> 6;
  const int col = blockIdx.y;
  const int qtile = (col < 16) ? (15 - (int)blockIdx.x) : (int)blockIdx.x;
  const int h = col & (NH - 1);
  const int b = col >> 4;
  const int q0 = qtile * 128;
  const int nkt = 2 * qtile + 2;
  const int lane_m = lane & 15, quad = lane >> 4, lane_k = quad * 8;

  // Q fragments (A-operand), one 16-row stripe per wave
  const int qrow = q0 + 16 * w + lane_m;
  const u16* qcp = Q + (size_t)(b * SQ + qrow) * LDQ + h * HD;
  const u16* qrp = Q + (size_t)(b * SQ + qrow) * LDQ + 2048 + h * RD;
  short8 qfc[4], qfr[2];
#pragma unroll
  for (int ks = 0; ks < 4; ks++) qfc[ks] = *(const short8*)(qcp + ks * 32 + lane_k);
#pragma unroll
  for (int ks = 0; ks < 2; ks++) qfr[ks] = *(const short8*)(qrp + ks * 32 + lane_k);

  floatx4 O[8] = {};
  float mrow[4], lsum[4];
#pragma unroll
  for (int r = 0; r < 4; r++) { mrow[r] = -1e30f; lsum[r] = 0.f; }

  const u16* gKc = KV + (size_t)b * SQ * LDKV + h * HD;          // + key*LDKV + d
  const u16* gKr = KV + (size_t)b * SQ * LDKV + 4096 + h * RD;   // + key*LDKV + d
  const u16* gVt = Vt + (size_t)(b * NH + h) * HD * SQ;          // + d*SQ + key
  const float C2 = 0.10412825525540364f;  // (1/sqrt(192)) * log2(e)
  const float THR = 28.8f;                // defer-max threshold: exp2(THR*C2)=8

  // register staging (global -> reg prefetch -> LDS), 512 threads
  short8 rKc[2], rKr, rVt[2];
  auto load_tile = [&](int kb) {
#pragma unroll
    for (int i = 0; i < 2; i++) {
      const int c = t + i * 512, row = c >> 4, cc = (c & 15) * 8;
      rKc[i] = *(const short8*)(gKc + (size_t)(kb + row) * LDKV + cc);
    }
    {
      const int row = t >> 3, cc = (t & 7) * 8;
      rKr = *(const short8*)(gKr + (size_t)(kb + row) * LDKV + cc);
    }
#pragma unroll
    for (int i = 0; i < 2; i++) {
      const int c = t + i * 512, row = c >> 3, cc = (c & 7) * 8;
      rVt[i] = *(const short8*)(gVt + (size_t)row * SQ + kb + cc);
    }
  };

  const int wrow_lo = q0 + 16 * w;
  const int wrow_hi = wrow_lo + 15;

  load_tile(0);
  for (int kt = 0; kt < nkt; kt++) {
    const int kb = kt * 64;
    __syncthreads();  // previous tile's LDS reads complete
#pragma unroll
    for (int i = 0; i < 2; i++) {
      const int c = t + i * 512, row = c >> 4, cc = (c & 15) * 8;
      *(short8*)(lKc + row * LKC + cc) = rKc[i];
    }
    {
      const int row = t >> 3, cc = (t & 7) * 8;
      *(short8*)(lKr + row * LKR + cc) = rKr;
    }
#pragma unroll
    for (int i = 0; i < 2; i++) {
      const int c = t + i * 512, row = c >> 3, cc = (c & 7) * 8;
      *(short8*)(lVt + row * LVT + cc) = rVt[i];
    }
    __syncthreads();
    if (kt < nkt - 1) load_tile(kb + 64);  // prefetch overlaps compute below

    if (kb <= wrow_hi) {  // wave-level skip of fully-masked tiles (barriers stay uniform)
      float ss[4][4];
      __builtin_amdgcn_s_setprio(1);
#pragma unroll
      for (int n = 0; n < 4; n++) {
        floatx4 a = {0.f, 0.f, 0.f, 0.f};
#pragma unroll
        for (int ks = 0; ks < 4; ks++) {
          const short8 kf = *(const short8*)(lKc + (n * 16 + lane_m) * LKC + ks * 32 + lane_k);
          a = __builtin_amdgcn_mfma_f32_16x16x32_bf16(qfc[ks], kf, a, 0, 0, 0);
        }
#pragma unroll
        for (int ks = 0; ks < 2; ks++) {
          const short8 kf = *(const short8*)(lKr + (n * 16 + lane_m) * LKR + ks * 32 + lane_k);
          a = __builtin_amdgcn_mfma_f32_16x16x32_bf16(qfr[ks], kf, a, 0, 0, 0);
        }
#pragma unroll
        for (int r = 0; r < 4; r++) ss[n][r] = a[r];
      }
      __builtin_amdgcn_s_setprio(0);
      if (kb + 63 > wrow_lo) {  // causal mask (partial tiles)
#pragma unroll
        for (int n = 0; n < 4; n++) {
          const int kcol = kb + n * 16 + lane_m;
#pragma unroll
          for (int r = 0; r < 4; r++) {
            const int row = wrow_lo + quad * 4 + r;
            if (kcol > row) ss[n][r] = -1e30f;
          }
        }
      }
      // per-row tile max
      float mt[4];
#pragma unroll
      for (int r = 0; r < 4; r++) {
        float m = fmaxf(fmaxf(ss[0][r], ss[1][r]), fmaxf(ss[2][r], ss[3][r]));
#pragma unroll
        for (int d = 1; d < 16; d <<= 1) m = fmaxf(m, __shfl_xor(m, d));
        mt[r] = m;
      }
      // T13 defer-max: rescale only if some row grew past THR
      const bool grow = (mt[0] > mrow[0] + THR) || (mt[1] > mrow[1] + THR) ||
                        (mt[2] > mrow[2] + THR) || (mt[3] > mrow[3] + THR);
      if (__any(grow)) {
#pragma unroll
        for (int r = 0; r < 4; r++) {
          const float mn = fmaxf(mrow[r], mt[r]);
          const float alpha = exp2f((mrow[r] - mn) * C2);
          mrow[r] = mn;
          lsum[r] *= alpha;
#pragma unroll
          for (int vb = 0; vb < 8; vb++) O[vb][r] *= alpha;
        }
      }
      float pw[4][4];
#pragma unroll
      for (int r = 0; r < 4; r++) {
        float s = 0.f;
#pragma unroll
        for (int n = 0; n < 4; n++) {
          const float p = exp2f((ss[n][r] - mrow[r]) * C2);
          pw[n][r] = p;
          s += p;
        }
#pragma unroll
        for (int d = 1; d < 16; d <<= 1) s += __shfl_xor(s, d);
        lsum[r] += s;
      }
      // P: C-layout -> LDS (per-wave region) -> A-layout
#pragma unroll
      for (int n = 0; n < 4; n++)
#pragma unroll
        for (int r = 0; r < 4; r++)
          lP[(w * 16 + quad * 4 + r) * LP + n * 16 + lane_m] = f2bf(pw[n][r]);
      asm volatile("s_waitcnt lgkmcnt(0)" ::: "memory");
      __builtin_amdgcn_s_setprio(1);
#pragma unroll
      for (int ks = 0; ks < 2; ks++) {
        const short8 pf = *(const short8*)(lP + (w * 16 + lane_m) * LP + ks * 32 + lane_k);
#pragma unroll
        for (int vb = 0; vb < 8; vb++) {
          const short8 vf = *(const short8*)(lVt + (vb * 16 + lane_m) * LVT + ks * 32 + lane_k);
          O[vb] = __builtin_amdgcn_mfma_f32_16x16x32_bf16(pf, vf, O[vb], 0, 0, 0);
        }
      }
      __builtin_amdgcn_s_setprio(0);
    }
  }
  float inv[4];
#pragma unroll
  for (int r = 0; r < 4; r++) inv[r] = 1.f / lsum[r];
#pragma unroll
  for (int vb = 0; vb < 8; vb++) {
#pragma unroll
    for (int r = 0; r < 4; r++) {
      const int row = wrow_lo + quad * 4 + r;
      Ctx[(size_t)(b * SQ + row) * 2048 + h * HD + vb * 16 + lane_m] = f2bf(O[vb][r] * inv[r]);
    }
  }
}

extern "C" void kernel_launch(void* const* d_in, const int* in_sizes, int n_in,
                              void* d_out, int out_size, void* d_ws, size_t ws_size,
                              hipStream_t stream) {
  (void)in_sizes; (void)n_in; (void)out_size; (void)ws_size;
  const float* x    = (const float*)d_in[0];
  const float* kvdw = (const float*)d_in[2];
  const float* kvdb = (const float*)d_in[3];
  const float* kuw  = (const float*)d_in[4];
  const float* kub  = (const float*)d_in[5];
  const float* vuw  = (const float*)d_in[6];
  const float* vub  = (const float*)d_in[7];
  const float* krw  = (const float*)d_in[8];
  const float* krb  = (const float*)d_in[9];
  const float* qdw  = (const float*)d_in[10];
  const float* qdb  = (const float*)d_in[11];
  const float* quw  = (const float*)d_in[12];
  const float* qub  = (const float*)d_in[13];
  const float* qrw  = (const float*)d_in[14];
  const float* qrb  = (const float*)d_in[15];
  const float* ow   = (const float*)d_in[16];
  const float* ob   = (const float*)d_in[17];

  // workspace layout (u16 units), ~115 MB, lifetime-aliased (see OFF_* macros)
  u16* ws   = (u16*)d_ws;
  u16* bc   = ws + OFF_BC;
  u16* WT1  = ws + OFF_WT1;
  u16* WT2  = ws + OFF_WT2;
  u16* WT3  = ws + OFF_WT3;
  u16* WTo  = ws + OFF_WTO;
  u16* KVQd = ws + OFF_KVQD;
  u16* KV   = ws + OFF_KV;
  u16* Qb   = ws + OFF_QB;
  u16* Ctx  = WT1;    // overlays WT1..WT3 (dead by flash)
  u16* Vt   = KVQd;   // overlays (dead after G3)
  u16* xc   = Qb;     // overlays Q (dead after G1)

  // one prep launch: convert_x + convert_biases + 8 weight transposes
  prep<<<dim3(23600), 256, 0, stream>>>(x, kvdb, qdb, kub, vub, krb, qub, qrb, ob,
                                        kvdw, qdw, kuw, vuw, krw, quw, qrw, ow, ws);

  auto G = [&](const u16* A, int lda, const u16* Bt, const u16* bias,
               void* Cout, int ldc, int wf32, int N, int K) {
    gemm_bt<<<dim3(N / 128, 4096 / 128), 512, 0, stream>>>(A, lda, Bt, bias, Cout, ldc, wf32, N, K);
  };
  G(xc, 2048, WT1, bc, KVQd, 2048, 0, 2048, 2048);                 // kv_c | q_c
  G(KVQd, 2048, WT2, bc + 2048, KV, LDKV, 0, 5120, 512);           // Kc | V | Kr
  G(KVQd + 512, 2048, WT3, bc + 7168, Qb, LDQ, 0, 3072, 1536);     // Qc | Qr

  // one post launch: rope(KV) + rope(Qb) + transpose_v
  post<<<dim3(24576), 256, 0, stream>>>(ws);

  flash_attn<<<dim3(16, 32), 512, 0, stream>>>(Qb, KV, Vt, Ctx);

  G(Ctx, 2048, WTo, bc + 10240, d_out, 2048, 1, 2048, 2048);       // out proj (f32)
}

// Round 10
// 471.689 us; speedup vs baseline: 1.1450x; 1.0710x over previous
//
#include <hip/hip_runtime.h>

typedef unsigned short u16;
typedef short short8 __attribute__((ext_vector_type(8)));
typedef short short4v __attribute__((ext_vector_type(4)));
typedef float floatx4 __attribute__((ext_vector_type(4)));
typedef float floatx4v __attribute__((ext_vector_type(4)));

#define SQ 2048
#define NH 16
#define HD 128
#define RD 64
#define NB 2
#define LDKV 5120
#define LDQ 3072

// padded LDS strides (odd multiples of 8 u16 = 16 B)
#define LKC 136
#define LKR 72
#define LVT 72
#define LP  72

// workspace offsets (u16 units) — shared by host launcher and merged kernels
#define OFF_BC   ((size_t)0)
#define OFF_WT1  ((size_t)16384)
#define OFF_WT2  (OFF_WT1 + (size_t)2048 * 2048)
#define OFF_WT3  (OFF_WT2 + (size_t)5120 * 512)
#define OFF_WTO  (OFF_WT3 + (size_t)3072 * 1536)
#define OFF_KVQD (OFF_WTO + (size_t)2048 * 2048)
#define OFF_KV   (OFF_KVQD + (size_t)4096 * 2048)
#define OFF_QB   (OFF_KV + (size_t)4096 * 5120)

__device__ __forceinline__ float bf2f(u16 u) {
  union { unsigned u; float f; } v; v.u = ((unsigned)u) << 16; return v.f;
}
__device__ __forceinline__ u16 f2bf(float f) {
  union { float f; unsigned u; } v; v.f = f;
  return (u16)((v.u + 0x7FFFu + ((v.u >> 16) & 1u)) >> 16);
}
__device__ __forceinline__ void gll16(const u16* g, u16* l) {
  __builtin_amdgcn_global_load_lds((const __attribute__((address_space(1))) void*)g,
                                   (__attribute__((address_space(3))) void*)l, 16, 0, 0);
}

// ---- prep: ONE launch = convert_x + convert_biases + all 8 weight transposes.
__global__ __launch_bounds__(256) void prep(
    const float* __restrict__ x,
    const float* b0, const float* b1, const float* b2, const float* b3,
    const float* b4, const float* b5, const float* b6, const float* b7,
    const float* w0, const float* w1, const float* w2, const float* w3,
    const float* w4, const float* w5, const float* w6, const float* w7,
    u16* __restrict__ ws) {
  __shared__ u16 tile[32][33];
  const int blk = blockIdx.x, t = threadIdx.x;

  if (blk < 8192) {  // convert_x: x f32 -> bf16 at xc (= Qb overlay)
    const int i = blk * 256 + t;  // exactly 4096*2048/4 threads
    const floatx4v v = *(const floatx4v*)(x + 4 * (size_t)i);
    short4v o;
    o.x = (short)f2bf(v.x); o.y = (short)f2bf(v.y);
    o.z = (short)f2bf(v.z); o.w = (short)f2bf(v.w);
    *(short4v*)(ws + OFF_QB + 4 * (size_t)i) = o;
    return;
  }
  if (blk < 8240) {  // biases -> bc
    const int i = (blk - 8192) * 256 + t;
    if (i >= 12288) return;
    float v;
    if      (i < 512)   v = b0[i];          // kvdb
    else if (i < 2048)  v = b1[i - 512];    // qdb
    else if (i < 4096)  v = b2[i - 2048];   // kub
    else if (i < 6144)  v = b3[i - 4096];   // vub
    else if (i < 7168)  v = b4[i - 6144];   // krb
    else if (i < 9216)  v = b5[i - 7168];   // qub
    else if (i < 10240) v = b6[i - 9216];   // qrb
    else                v = b7[i - 10240];  // ob
    ws[OFF_BC + i] = f2bf(v);
    return;
  }
  // weight transposes: in[R][C] f32 -> out[C][R] bf16
  const int f = blk - 8240;  // [0, 15360)
  const float* in; size_t oo; int R, C, start;
  if      (f < 1024)  { in = w0; oo = OFF_WT1;                        R = 2048; C = 512;  start = 0; }
  else if (f < 4096)  { in = w1; oo = OFF_WT1 + (size_t)512 * 2048;   R = 2048; C = 1536; start = 1024; }
  else if (f < 5120)  { in = w2; oo = OFF_WT2;                        R = 512;  C = 2048; start = 4096; }
  else if (f < 6144)  { in = w3; oo = OFF_WT2 + (size_t)2048 * 512;   R = 512;  C = 2048; start = 5120; }
  else if (f < 6656)  { in = w4; oo = OFF_WT2 + (size_t)4096 * 512;   R = 512;  C = 1024; start = 6144; }
  else if (f < 9728)  { in = w5; oo = OFF_WT3;                        R = 1536; C = 2048; start = 6656; }
  else if (f < 11264) { in = w6; oo = OFF_WT3 + (size_t)2048 * 1536;  R = 1536; C = 1024; start = 9728; }
  else                { in = w7; oo = OFF_WTO;                        R = 2048; C = 2048; start = 11264; }
  u16* out = ws + oo;
  const int local = f - start, nx = C / 32;
  const int c0 = (local % nx) * 32, r0 = (local / nx) * 32;
  const int xx = t & 31, y = t >> 5;
#pragma unroll
  for (int i = 0; i < 32; i += 8)
    tile[y + i][xx] = f2bf(in[(size_t)(r0 + y + i) * C + c0 + xx]);
  __syncthreads();
#pragma unroll
  for (int i = 0; i < 32; i += 8)
    out[(size_t)(c0 + y + i) * R + r0 + xx] = tile[xx][y + i];
}

// ---- post: ONE launch = rope(KV) + transpose_v.
// r10: rope(Qb) moved into flash_attn's Q-fragment load (lane-local pairs);
// post shrinks 24576 -> 16384 blocks. Disjoint regions: rope-KV writes KV cols
// 4096+, transpose_v reads KV cols 2048..4095 -> any block order is safe.
__global__ __launch_bounds__(256) void post(u16* __restrict__ ws) {
  __shared__ u16 tile[32][33];
  const int blk = blockIdx.x, t = threadIdx.x;

  if (blk < 8192) {  // rope in place on KV rope cols
    u16* buf = ws + OFF_KV;
    const int i = blk * 256 + t;  // exactly NB*SQ*NH*32 threads
    const int j = i & 31;
    const int hh = (i >> 5) & 15;
    const int row = i >> 9;
    const int s = row & (SQ - 1);
    u16* p = buf + (size_t)row * LDKV + 4096 + hh * RD + 2 * j;
    const float x1 = bf2f(p[0]), x2 = bf2f(p[1]);
    const float inv = exp2f(-(float)j * 0.41524101186092031f);  // 10000^(-j/32)
    const float ang = (float)s * inv;
    float sn, cs;
    sincosf(ang, &sn, &cs);
    p[0] = f2bf(x1 * cs - x2 * sn);
    p[1] = f2bf(x1 * sn + x2 * cs);
    return;
  }
  // transpose_v: V (cols 2048..4095 of KV) -> Vt [B,H,HD,S] (= KVQd overlay)
  const int f = blk - 8192;             // [0, 8192)
  const int bh = f >> 8, rem = f & 255;
  const int b = bh >> 4, hh = bh & 15;
  const int s0 = (rem & 63) * 32, d0 = (rem >> 6) * 32;
  const u16* pin = ws + OFF_KV + (size_t)b * SQ * LDKV + 2048 + (size_t)hh * HD;
  u16* pout = ws + OFF_KVQD + (size_t)bh * HD * SQ;
  const int xx = t & 31, y = t >> 5;
#pragma unroll
  for (int i = 0; i < 32; i += 8)
    tile[y + i][xx] = pin[(size_t)(s0 + y + i) * LDKV + d0 + xx];
  __syncthreads();
#pragma unroll
  for (int i = 0; i < 32; i += 8)
    pout[(size_t)(d0 + y + i) * SQ + s0 + xx] = tile[xx][y + i];
}

// ---- C[M=4096,N] = A[.,K](lda) * Bt[N,K]^T + bias; out bf16(ldc) or f32 ----
// r7's exact proven body (8 waves / 512 thr per 128^2 tile, BK=64 split K-half
// buffers, linear gll16 dests). r10: generalized to TWO param sets selected by
// block id vs `split` (scalar SGPR select — no array/lambda codegen risk), so
// independent GEMMs (G2, G3) fuse into one launch: G2's tail scheduling round
// overlaps G3's head (~1 full round saved at 2 blocks/CU). 1D grid; id order
// dispatches set-1 blocks first.
__global__ __launch_bounds__(512, 4) void gemm_bt(
    int split,
    const u16* __restrict__ A1, int lda1, const u16* __restrict__ B1,
    const u16* __restrict__ bias1, void* __restrict__ C1, int ldc1, int wf1, int N1, int K1,
    const u16* __restrict__ A2, int lda2, const u16* __restrict__ B2,
    const u16* __restrict__ bias2, void* __restrict__ C2, int ldc2, int wf2, int N2, int K2) {
  __shared__ __align__(16) u16 lAk0[128 * 32];
  __shared__ __align__(16) u16 lAk1[128 * 32];
  __shared__ __align__(16) u16 lBk0[128 * 32];
  __shared__ __align__(16) u16 lBk1[128 * 32];
  int id = blockIdx.x;
  const u16 *A, *Bt, *bias; void* Cout; int lda, ldc, wf32, N, K;
  if (id < split) {
    A = A1; lda = lda1; Bt = B1; bias = bias1; Cout = C1; ldc = ldc1; wf32 = wf1; N = N1; K = K1;
  } else {
    id -= split;
    A = A2; lda = lda2; Bt = B2; bias = bias2; Cout = C2; ldc = ldc2; wf32 = wf2; N = N2; K = K2;
  }
  const int nx = N >> 7;
  const int m0 = (id / nx) * 128, n0 = (id % nx) * 128;
  const int t = threadIdx.x;
  const int lane = t & 63, w = t >> 6;      // 8 waves
  const int wm = w & 1, wn = w >> 1;        // 2 M-halves x 4 N-quarters
  const int srow = t >> 2, scol = (t & 3) * 8;  // 512 thr cover [128][32] once
  const u16* gA = A + (size_t)(m0 + srow) * lda + scol;
  const u16* gB = Bt + (size_t)(n0 + srow) * K + scol;
  u16* const ldA0 = lAk0 + (16 * w) * 32;   // wave-uniform gll16 dests
  u16* const ldA1 = lAk1 + (16 * w) * 32;
  u16* const ldB0 = lBk0 + (16 * w) * 32;
  u16* const ldB1 = lBk1 + (16 * w) * 32;
  const int lane_m = lane & 15, lane_k = (lane >> 4) * 8;
  floatx4 acc[4][2] = {};
  for (int k0 = 0; k0 < K; k0 += 64) {
    gll16(gA + k0, ldA0);
    gll16(gA + k0 + 32, ldA1);
    gll16(gB + k0, ldB0);
    gll16(gB + k0 + 32, ldB1);
    __syncthreads();
    {
      short8 af[4], bf[2];
#pragma unroll
      for (int i = 0; i < 4; i++)
        af[i] = *(const short8*)(lAk0 + (wm * 64 + i * 16 + lane_m) * 32 + lane_k);
#pragma unroll
      for (int i = 0; i < 2; i++)
        bf[i] = *(const short8*)(lBk0 + (wn * 32 + i * 16 + lane_m) * 32 + lane_k);
#pragma unroll
      for (int mi = 0; mi < 4; mi++)
#pragma unroll
        for (int ni = 0; ni < 2; ni++)
          acc[mi][ni] = __builtin_amdgcn_mfma_f32_16x16x32_bf16(af[mi], bf[ni], acc[mi][ni], 0, 0, 0);
    }
    {
      short8 af[4], bf[2];
#pragma unroll
      for (int i = 0; i < 4; i++)
        af[i] = *(const short8*)(lAk1 + (wm * 64 + i * 16 + lane_m) * 32 + lane_k);
#pragma unroll
      for (int i = 0; i < 2; i++)
        bf[i] = *(const short8*)(lBk1 + (wn * 32 + i * 16 + lane_m) * 32 + lane_k);
#pragma unroll
      for (int mi = 0; mi < 4; mi++)
#pragma unroll
        for (int ni = 0; ni < 2; ni++)
          acc[mi][ni] = __builtin_amdgcn_mfma_f32_16x16x32_bf16(af[mi], bf[ni], acc[mi][ni], 0, 0, 0);
    }
    __syncthreads();
  }
  const int quad = lane >> 4;
#pragma unroll
  for (int ni = 0; ni < 2; ni++) {
    const int col = n0 + wn * 32 + ni * 16 + lane_m;
    const float bv = bf2f(bias[col]);
#pragma unroll
    for (int mi = 0; mi < 4; mi++) {
      const int row = m0 + wm * 64 + mi * 16 + quad * 4;
      if (wf32) {
        float* pc = (float*)Cout + (size_t)row * ldc + col;
#pragma unroll
        for (int r = 0; r < 4; r++)
          pc[(size_t)r * ldc] = acc[mi][ni][r] + bv;
      } else {
        u16* pc = (u16*)Cout + (size_t)row * ldc + col;
#pragma unroll
        for (int r = 0; r < 4; r++)
          pc[(size_t)r * ldc] = f2bf(acc[mi][ni][r] + bv);
      }
    }
  }
}

// ---- flash attention: grid (16, 32); 8 waves, 128 q-rows/block, 64-key tiles ----
// Verified r5-r9 structure (156 us). r10 addition: RoPE on the q_r fragments is
// applied IN-REGISTER at load (pairs (2j,2j+1) are lane-local: d = ks*32+quad*8+e
// -> j = ks*16+quad*4+p, all static after unroll). Replaces the rope_inplace
// pass over Qb (8192 blocks + 17 MB traffic). Same bf16->f32->rope->bf16
// rounding path as before -> bit-identical output.
__global__ __launch_bounds__(512, 4) void flash_attn(const u16* __restrict__ Q,
                                                     const u16* __restrict__ KV,
                                                     const u16* __restrict__ Vt,
                                                     u16* __restrict__ Ctx) {
  __shared__ __align__(16) u16 lKc[64 * LKC];
  __shared__ __align__(16) u16 lKr[64 * LKR];
  __shared__ __align__(16) u16 lVt[128 * LVT];
  __shared__ __align__(16) u16 lP[8 * 16 * LP];
  const int t = threadIdx.x, lane = t & 63, w = t >> 6;
  const int col = blockIdx.y;
  const int qtile = (col < 16) ? (15 - (int)blockIdx.x) : (int)blockIdx.x;
  const int h = col & (NH - 1);
  const int b = col >> 4;
  const int q0 = qtile * 128;
  const int nkt = 2 * qtile + 2;
  const int lane_m = lane & 15, quad = lane >> 4, lane_k = quad * 8;

  // Q fragments (A-operand), one 16-row stripe per wave
  const int qrow = q0 + 16 * w + lane_m;
  const u16* qcp = Q + (size_t)(b * SQ + qrow) * LDQ + h * HD;
  const u16* qrp = Q + (size_t)(b * SQ + qrow) * LDQ + 2048 + h * RD;
  short8 qfc[4], qfr[2];
#pragma unroll
  for (int ks = 0; ks < 4; ks++) qfc[ks] = *(const short8*)(qcp + ks * 32 + lane_k);
  {
    const float sp = (float)qrow;  // sequence position (qrow in [0, SQ))
#pragma unroll
    for (int ks = 0; ks < 2; ks++) {
      short8 v = *(const short8*)(qrp + ks * 32 + lane_k);
#pragma unroll
      for (int p = 0; p < 4; p++) {
        const int j = ks * 16 + quad * 4 + p;  // rope pair index in [0,32)
        const float inv = exp2f(-(float)j * 0.41524101186092031f);  // 10000^(-j/32)
        float sn, cs;
        sincosf(sp * inv, &sn, &cs);
        const float x1 = bf2f((u16)v[2 * p]), x2 = bf2f((u16)v[2 * p + 1]);
        v[2 * p]     = (short)f2bf(x1 * cs - x2 * sn);
        v[2 * p + 1] = (short)f2bf(x1 * sn + x2 * cs);
      }
      qfr[ks] = v;
    }
  }

  floatx4 O[8] = {};
  float mrow[4], lsum[4];
#pragma unroll
  for (int r = 0; r < 4; r++) { mrow[r] = -1e30f; lsum[r] = 0.f; }

  const u16* gKc = KV + (size_t)b * SQ * LDKV + h * HD;          // + key*LDKV + d
  const u16* gKr = KV + (size_t)b * SQ * LDKV + 4096 + h * RD;   // + key*LDKV + d
  const u16* gVt = Vt + (size_t)(b * NH + h) * HD * SQ;          // + d*SQ + key
  const float C2 = 0.10412825525540364f;  // (1/sqrt(192)) * log2(e)
  const float THR = 28.8f;                // defer-max threshold: exp2(THR*C2)=8

  // register staging (global -> reg prefetch -> LDS), 512 threads
  short8 rKc[2], rKr, rVt[2];
  auto load_tile = [&](int kb) {
#pragma unroll
    for (int i = 0; i < 2; i++) {
      const int c = t + i * 512, row = c >> 4, cc = (c & 15) * 8;
      rKc[i] = *(const short8*)(gKc + (size_t)(kb + row) * LDKV + cc);
    }
    {
      const int row = t >> 3, cc = (t & 7) * 8;
      rKr = *(const short8*)(gKr + (size_t)(kb + row) * LDKV + cc);
    }
#pragma unroll
    for (int i = 0; i < 2; i++) {
      const int c = t + i * 512, row = c >> 3, cc = (c & 7) * 8;
      rVt[i] = *(const short8*)(gVt + (size_t)row * SQ + kb + cc);
    }
  };

  const int wrow_lo = q0 + 16 * w;
  const int wrow_hi = wrow_lo + 15;

  load_tile(0);
  for (int kt = 0; kt < nkt; kt++) {
    const int kb = kt * 64;
    __syncthreads();  // previous tile's LDS reads complete
#pragma unroll
    for (int i = 0; i < 2; i++) {
      const int c = t + i * 512, row = c >> 4, cc = (c & 15) * 8;
      *(short8*)(lKc + row * LKC + cc) = rKc[i];
    }
    {
      const int row = t >> 3, cc = (t & 7) * 8;
      *(short8*)(lKr + row * LKR + cc) = rKr;
    }
#pragma unroll
    for (int i = 0; i < 2; i++) {
      const int c = t + i * 512, row = c >> 3, cc = (c & 7) * 8;
      *(short8*)(lVt + row * LVT + cc) = rVt[i];
    }
    __syncthreads();
    if (kt < nkt - 1) load_tile(kb + 64);  // prefetch overlaps compute below

    if (kb <= wrow_hi) {  // wave-level skip of fully-masked tiles (barriers stay uniform)
      float ss[4][4];
      __builtin_amdgcn_s_setprio(1);
#pragma unroll
      for (int n = 0; n < 4; n++) {
        floatx4 a = {0.f, 0.f, 0.f, 0.f};
#pragma unroll
        for (int ks = 0; ks < 4; ks++) {
          const short8 kf = *(const short8*)(lKc + (n * 16 + lane_m) * LKC + ks * 32 + lane_k);
          a = __builtin_amdgcn_mfma_f32_16x16x32_bf16(qfc[ks], kf, a, 0, 0, 0);
        }
#pragma unroll
        for (int ks = 0; ks < 2; ks++) {
          const short8 kf = *(const short8*)(lKr + (n * 16 + lane_m) * LKR + ks * 32 + lane_k);
          a = __builtin_amdgcn_mfma_f32_16x16x32_bf16(qfr[ks], kf, a, 0, 0, 0);
        }
#pragma unroll
        for (int r = 0; r < 4; r++) ss[n][r] = a[r];
      }
      __builtin_amdgcn_s_setprio(0);
      if (kb + 63 > wrow_lo) {  // causal mask (partial tiles)
#pragma unroll
        for (int n = 0; n < 4; n++) {
          const int kcol = kb + n * 16 + lane_m;
#pragma unroll
          for (int r = 0; r < 4; r++) {
            const int row = wrow_lo + quad * 4 + r;
            if (kcol > row) ss[n][r] = -1e30f;
          }
        }
      }
      // per-row tile max
      float mt[4];
#pragma unroll
      for (int r = 0; r < 4; r++) {
        float m = fmaxf(fmaxf(ss[0][r], ss[1][r]), fmaxf(ss[2][r], ss[3][r]));
#pragma unroll
        for (int d = 1; d < 16; d <<= 1) m = fmaxf(m, __shfl_xor(m, d));
        mt[r] = m;
      }
      // T13 defer-max: rescale only if some row grew past THR
      const bool grow = (mt[0] > mrow[0] + THR) || (mt[1] > mrow[1] + THR) ||
                        (mt[2] > mrow[2] + THR) || (mt[3] > mrow[3] + THR);
      if (__any(grow)) {
#pragma unroll
        for (int r = 0; r < 4; r++) {
          const float mn = fmaxf(mrow[r], mt[r]);
          const float alpha = exp2f((mrow[r] - mn) * C2);
          mrow[r] = mn;
          lsum[r] *= alpha;
#pragma unroll
          for (int vb = 0; vb < 8; vb++) O[vb][r] *= alpha;
        }
      }
      float pw[4][4];
#pragma unroll
      for (int r = 0; r < 4; r++) {
        float s = 0.f;
#pragma unroll
        for (int n = 0; n < 4; n++) {
          const float p = exp2f((ss[n][r] - mrow[r]) * C2);
          pw[n][r] = p;
          s += p;
        }
#pragma unroll
        for (int d = 1; d < 16; d <<= 1) s += __shfl_xor(s, d);
        lsum[r] += s;
      }
      // P: C-layout -> LDS (per-wave region) -> A-layout
#pragma unroll
      for (int n = 0; n < 4; n++)
#pragma unroll
        for (int r = 0; r < 4; r++)
          lP[(w * 16 + quad * 4 + r) * LP + n * 16 + lane_m] = f2bf(pw[n][r]);
      asm volatile("s_waitcnt lgkmcnt(0)" ::: "memory");
      __builtin_amdgcn_s_setprio(1);
#pragma unroll
      for (int ks = 0; ks < 2; ks++) {
        const short8 pf = *(const short8*)(lP + (w * 16 + lane_m) * LP + ks * 32 + lane_k);
#pragma unroll
        for (int vb = 0; vb < 8; vb++) {
          const short8 vf = *(const short8*)(lVt + (vb * 16 + lane_m) * LVT + ks * 32 + lane_k);
          O[vb] = __builtin_amdgcn_mfma_f32_16x16x32_bf16(pf, vf, O[vb], 0, 0, 0);
        }
      }
      __builtin_amdgcn_s_setprio(0);
    }
  }
  float inv[4];
#pragma unroll
  for (int r = 0; r < 4; r++) inv[r] = 1.f / lsum[r];
#pragma unroll
  for (int vb = 0; vb < 8; vb++) {
#pragma unroll
    for (int r = 0; r < 4; r++) {
      const int row = wrow_lo + quad * 4 + r;
      Ctx[(size_t)(b * SQ + row) * 2048 + h * HD + vb * 16 + lane_m] = f2bf(O[vb][r] * inv[r]);
    }
  }
}

extern "C" void kernel_launch(void* const* d_in, const int* in_sizes, int n_in,
                              void* d_out, int out_size, void* d_ws, size_t ws_size,
                              hipStream_t stream) {
  (void)in_sizes; (void)n_in; (void)out_size; (void)ws_size;
  const float* x    = (const float*)d_in[0];
  const float* kvdw = (const float*)d_in[2];
  const float* kvdb = (const float*)d_in[3];
  const float* kuw  = (const float*)d_in[4];
  const float* kub  = (const float*)d_in[5];
  const float* vuw  = (const float*)d_in[6];
  const float* vub  = (const float*)d_in[7];
  const float* krw  = (const float*)d_in[8];
  const float* krb  = (const float*)d_in[9];
  const float* qdw  = (const float*)d_in[10];
  const float* qdb  = (const float*)d_in[11];
  const float* quw  = (const float*)d_in[12];
  const float* qub  = (const float*)d_in[13];
  const float* qrw  = (const float*)d_in[14];
  const float* qrb  = (const float*)d_in[15];
  const float* ow   = (const float*)d_in[16];
  const float* ob   = (const float*)d_in[17];

  // workspace layout (u16 units), ~115 MB, lifetime-aliased (see OFF_* macros)
  u16* ws   = (u16*)d_ws;
  u16* bc   = ws + OFF_BC;
  u16* WT1  = ws + OFF_WT1;
  u16* WT2  = ws + OFF_WT2;
  u16* WT3  = ws + OFF_WT3;
  u16* WTo  = ws + OFF_WTO;
  u16* KVQd = ws + OFF_KVQD;
  u16* KV   = ws + OFF_KV;
  u16* Qb   = ws + OFF_QB;
  u16* Ctx  = WT1;    // overlays WT1..WT3 (dead by flash)
  u16* Vt   = KVQd;   // overlays (dead after G3)
  u16* xc   = Qb;     // overlays Q (dead after G1)
  const u16* nu = (const u16*)nullptr;

  // one prep launch: convert_x + convert_biases + 8 weight transposes
  prep<<<dim3(23600), 256, 0, stream>>>(x, kvdb, qdb, kub, vub, krb, qub, qrb, ob,
                                        kvdw, qdw, kuw, vuw, krw, quw, qrw, ow, ws);

  // G1: kv_c | q_c   (512 blocks, single param set)
  gemm_bt<<<dim3(512), 512, 0, stream>>>(1 << 30,
      xc, 2048, WT1, bc, KVQd, 2048, 0, 2048, 2048,
      nu, 0, nu, nu, (void*)nullptr, 0, 0, 0, 64);

  // G2+G3 fused: G2 = Kc|V|Kr (1280 blocks, ids 0..1279), G3 = Qc|Qr (768)
  gemm_bt<<<dim3(2048), 512, 0, stream>>>(1280,
      KVQd, 2048, WT2, bc + 2048, KV, LDKV, 0, 5120, 512,
      KVQd + 512, 2048, WT3, bc + 7168, Qb, LDQ, 0, 3072, 1536);

  // one post launch: rope(KV) + transpose_v   (rope-Q folded into flash)
  post<<<dim3(16384), 256, 0, stream>>>(ws);

  flash_attn<<<dim3(16, 32), 512, 0, stream>>>(Qb, KV, Vt, Ctx);

  // G4: out proj (f32 out)
  gemm_bt<<<dim3(512), 512, 0, stream>>>(1 << 30,
      Ctx, 2048, WTo, bc + 10240, d_out, 2048, 1, 2048, 2048,
      nu, 0, nu, nu, (void*)nullptr, 0, 0, 0, 64);
}

// Round 11
// 468.831 us; speedup vs baseline: 1.1520x; 1.0061x over previous
//
#include <hip/hip_runtime.h>

typedef unsigned short u16;
typedef short short8 __attribute__((ext_vector_type(8)));
typedef short short4v __attribute__((ext_vector_type(4)));
typedef float floatx4 __attribute__((ext_vector_type(4)));
typedef float floatx4v __attribute__((ext_vector_type(4)));

#define SQ 2048
#define NH 16
#define HD 128
#define RD 64
#define NB 2
#define LDKV 5120
#define LDQ 3072

// padded LDS strides (odd multiples of 8 u16 = 16 B)
#define LKC 136
#define LKR 72
#define LVT 72
#define LP  72

// workspace offsets (u16 units) — shared by host launcher and merged kernels
#define OFF_BC   ((size_t)0)
#define OFF_WT1  ((size_t)16384)
#define OFF_WT2  (OFF_WT1 + (size_t)2048 * 2048)
#define OFF_WT3  (OFF_WT2 + (size_t)5120 * 512)
#define OFF_WTO  (OFF_WT3 + (size_t)3072 * 1536)
#define OFF_KVQD (OFF_WTO + (size_t)2048 * 2048)
#define OFF_KV   (OFF_KVQD + (size_t)4096 * 2048)
#define OFF_QB   (OFF_KV + (size_t)4096 * 5120)
#define OFF_ROPE (OFF_QB + (size_t)4096 * 3072)   // 2048x32 float2 = 512 KB

__device__ __forceinline__ float bf2f(u16 u) {
  union { unsigned u; float f; } v; v.u = ((unsigned)u) << 16; return v.f;
}
__device__ __forceinline__ u16 f2bf(float f) {
  union { float f; unsigned u; } v; v.f = f;
  return (u16)((v.u + 0x7FFFu + ((v.u >> 16) & 1u)) >> 16);
}
__device__ __forceinline__ void gll16(const u16* g, u16* l) {
  __builtin_amdgcn_global_load_lds((const __attribute__((address_space(1))) void*)g,
                                   (__attribute__((address_space(3))) void*)l, 16, 0, 0);
}

// ---- prep: ONE launch = convert_x + biases + 8 weight transposes + rope table.
// r11: rope cos/sin table (2048 pos x 32 pairs, f32) precomputed here — r10's
// in-register sincosf in flash_attn cost 12 us of VALU (guide: precompute trig
// tables, m205). Table values computed with the SAME sincosf -> downstream
// output bit-identical to r10.
__global__ __launch_bounds__(256) void prep(
    const float* __restrict__ x,
    const float* b0, const float* b1, const float* b2, const float* b3,
    const float* b4, const float* b5, const float* b6, const float* b7,
    const float* w0, const float* w1, const float* w2, const float* w3,
    const float* w4, const float* w5, const float* w6, const float* w7,
    u16* __restrict__ ws) {
  __shared__ u16 tile[32][33];
  const int blk = blockIdx.x, t = threadIdx.x;

  if (blk < 8192) {  // convert_x: x f32 -> bf16 at xc (= Qb overlay)
    const int i = blk * 256 + t;  // exactly 4096*2048/4 threads
    const floatx4v v = *(const floatx4v*)(x + 4 * (size_t)i);
    short4v o;
    o.x = (short)f2bf(v.x); o.y = (short)f2bf(v.y);
    o.z = (short)f2bf(v.z); o.w = (short)f2bf(v.w);
    *(short4v*)(ws + OFF_QB + 4 * (size_t)i) = o;
    return;
  }
  if (blk < 8240) {  // biases -> bc
    const int i = (blk - 8192) * 256 + t;
    if (i >= 12288) return;
    float v;
    if      (i < 512)   v = b0[i];          // kvdb
    else if (i < 2048)  v = b1[i - 512];    // qdb
    else if (i < 4096)  v = b2[i - 2048];   // kub
    else if (i < 6144)  v = b3[i - 4096];   // vub
    else if (i < 7168)  v = b4[i - 6144];   // krb
    else if (i < 9216)  v = b5[i - 7168];   // qub
    else if (i < 10240) v = b6[i - 9216];   // qrb
    else                v = b7[i - 10240];  // ob
    ws[OFF_BC + i] = f2bf(v);
    return;
  }
  if (blk >= 23600) {  // rope table: i = s*32 + j, entry = (cos, sin)
    const int i = (blk - 23600) * 256 + t;  // [0, 65536)
    const int s = i >> 5, j = i & 31;
    const float inv = exp2f(-(float)j * 0.41524101186092031f);  // 10000^(-j/32)
    float sn, cs;
    sincosf((float)s * inv, &sn, &cs);
    float* rt = (float*)(ws + OFF_ROPE);
    rt[2 * i]     = cs;
    rt[2 * i + 1] = sn;
    return;
  }
  // weight transposes: in[R][C] f32 -> out[C][R] bf16
  const int f = blk - 8240;  // [0, 15360)
  const float* in; size_t oo; int R, C, start;
  if      (f < 1024)  { in = w0; oo = OFF_WT1;                        R = 2048; C = 512;  start = 0; }
  else if (f < 4096)  { in = w1; oo = OFF_WT1 + (size_t)512 * 2048;   R = 2048; C = 1536; start = 1024; }
  else if (f < 5120)  { in = w2; oo = OFF_WT2;                        R = 512;  C = 2048; start = 4096; }
  else if (f < 6144)  { in = w3; oo = OFF_WT2 + (size_t)2048 * 512;   R = 512;  C = 2048; start = 5120; }
  else if (f < 6656)  { in = w4; oo = OFF_WT2 + (size_t)4096 * 512;   R = 512;  C = 1024; start = 6144; }
  else if (f < 9728)  { in = w5; oo = OFF_WT3;                        R = 1536; C = 2048; start = 6656; }
  else if (f < 11264) { in = w6; oo = OFF_WT3 + (size_t)2048 * 1536;  R = 1536; C = 1024; start = 9728; }
  else                { in = w7; oo = OFF_WTO;                        R = 2048; C = 2048; start = 11264; }
  u16* out = ws + oo;
  const int local = f - start, nx = C / 32;
  const int c0 = (local % nx) * 32, r0 = (local / nx) * 32;
  const int xx = t & 31, y = t >> 5;
#pragma unroll
  for (int i = 0; i < 32; i += 8)
    tile[y + i][xx] = f2bf(in[(size_t)(r0 + y + i) * C + c0 + xx]);
  __syncthreads();
#pragma unroll
  for (int i = 0; i < 32; i += 8)
    out[(size_t)(c0 + y + i) * R + r0 + xx] = tile[xx][y + i];
}

// ---- post: ONE launch = rope(KV) (table-driven) + transpose_v.
__global__ __launch_bounds__(256) void post(u16* __restrict__ ws) {
  __shared__ u16 tile[32][33];
  const int blk = blockIdx.x, t = threadIdx.x;

  if (blk < 8192) {  // rope in place on KV rope cols, via table
    u16* buf = ws + OFF_KV;
    const float* rt = (const float*)(ws + OFF_ROPE);
    const int i = blk * 256 + t;  // exactly NB*SQ*NH*32 threads
    const int j = i & 31;
    const int hh = (i >> 5) & 15;
    const int row = i >> 9;
    const int s = row & (SQ - 1);
    u16* p = buf + (size_t)row * LDKV + 4096 + hh * RD + 2 * j;
    const float2 t2 = *(const float2*)(rt + ((size_t)s * 32 + j) * 2);
    const float x1 = bf2f(p[0]), x2 = bf2f(p[1]);
    p[0] = f2bf(x1 * t2.x - x2 * t2.y);
    p[1] = f2bf(x1 * t2.y + x2 * t2.x);
    return;
  }
  // transpose_v: V (cols 2048..4095 of KV) -> Vt [B,H,HD,S] (= KVQd overlay)
  const int f = blk - 8192;             // [0, 8192)
  const int bh = f >> 8, rem = f & 255;
  const int b = bh >> 4, hh = bh & 15;
  const int s0 = (rem & 63) * 32, d0 = (rem >> 6) * 32;
  const u16* pin = ws + OFF_KV + (size_t)b * SQ * LDKV + 2048 + (size_t)hh * HD;
  u16* pout = ws + OFF_KVQD + (size_t)bh * HD * SQ;
  const int xx = t & 31, y = t >> 5;
#pragma unroll
  for (int i = 0; i < 32; i += 8)
    tile[y + i][xx] = pin[(size_t)(s0 + y + i) * LDKV + d0 + xx];
  __syncthreads();
#pragma unroll
  for (int i = 0; i < 32; i += 8)
    pout[(size_t)(d0 + y + i) * SQ + s0 + xx] = tile[xx][y + i];
}

// ---- C[M=4096,N] = A[.,K](lda) * Bt[N,K]^T + bias; out bf16(ldc) or f32 ----
// r7's proven body (8 waves / 512 thr per 128^2 tile, BK=64 split K-half
// buffers, linear gll16 dests). Two param sets selected by block id vs `split`
// (scalar SGPR select) so independent GEMMs fuse into one launch (r10: -~15us).
__global__ __launch_bounds__(512, 4) void gemm_bt(
    int split,
    const u16* __restrict__ A1, int lda1, const u16* __restrict__ B1,
    const u16* __restrict__ bias1, void* __restrict__ C1, int ldc1, int wf1, int N1, int K1,
    const u16* __restrict__ A2, int lda2, const u16* __restrict__ B2,
    const u16* __restrict__ bias2, void* __restrict__ C2, int ldc2, int wf2, int N2, int K2) {
  __shared__ __align__(16) u16 lAk0[128 * 32];
  __shared__ __align__(16) u16 lAk1[128 * 32];
  __shared__ __align__(16) u16 lBk0[128 * 32];
  __shared__ __align__(16) u16 lBk1[128 * 32];
  int id = blockIdx.x;
  const u16 *A, *Bt, *bias; void* Cout; int lda, ldc, wf32, N, K;
  if (id < split) {
    A = A1; lda = lda1; Bt = B1; bias = bias1; Cout = C1; ldc = ldc1; wf32 = wf1; N = N1; K = K1;
  } else {
    id -= split;
    A = A2; lda = lda2; Bt = B2; bias = bias2; Cout = C2; ldc = ldc2; wf32 = wf2; N = N2; K = K2;
  }
  const int nx = N >> 7;
  const int m0 = (id / nx) * 128, n0 = (id % nx) * 128;
  const int t = threadIdx.x;
  const int lane = t & 63, w = t >> 6;      // 8 waves
  const int wm = w & 1, wn = w >> 1;        // 2 M-halves x 4 N-quarters
  const int srow = t >> 2, scol = (t & 3) * 8;  // 512 thr cover [128][32] once
  const u16* gA = A + (size_t)(m0 + srow) * lda + scol;
  const u16* gB = Bt + (size_t)(n0 + srow) * K + scol;
  u16* const ldA0 = lAk0 + (16 * w) * 32;   // wave-uniform gll16 dests
  u16* const ldA1 = lAk1 + (16 * w) * 32;
  u16* const ldB0 = lBk0 + (16 * w) * 32;
  u16* const ldB1 = lBk1 + (16 * w) * 32;
  const int lane_m = lane & 15, lane_k = (lane >> 4) * 8;
  floatx4 acc[4][2] = {};
  for (int k0 = 0; k0 < K; k0 += 64) {
    gll16(gA + k0, ldA0);
    gll16(gA + k0 + 32, ldA1);
    gll16(gB + k0, ldB0);
    gll16(gB + k0 + 32, ldB1);
    __syncthreads();
    {
      short8 af[4], bf[2];
#pragma unroll
      for (int i = 0; i < 4; i++)
        af[i] = *(const short8*)(lAk0 + (wm * 64 + i * 16 + lane_m) * 32 + lane_k);
#pragma unroll
      for (int i = 0; i < 2; i++)
        bf[i] = *(const short8*)(lBk0 + (wn * 32 + i * 16 + lane_m) * 32 + lane_k);
#pragma unroll
      for (int mi = 0; mi < 4; mi++)
#pragma unroll
        for (int ni = 0; ni < 2; ni++)
          acc[mi][ni] = __builtin_amdgcn_mfma_f32_16x16x32_bf16(af[mi], bf[ni], acc[mi][ni], 0, 0, 0);
    }
    {
      short8 af[4], bf[2];
#pragma unroll
      for (int i = 0; i < 4; i++)
        af[i] = *(const short8*)(lAk1 + (wm * 64 + i * 16 + lane_m) * 32 + lane_k);
#pragma unroll
      for (int i = 0; i < 2; i++)
        bf[i] = *(const short8*)(lBk1 + (wn * 32 + i * 16 + lane_m) * 32 + lane_k);
#pragma unroll
      for (int mi = 0; mi < 4; mi++)
#pragma unroll
        for (int ni = 0; ni < 2; ni++)
          acc[mi][ni] = __builtin_amdgcn_mfma_f32_16x16x32_bf16(af[mi], bf[ni], acc[mi][ni], 0, 0, 0);
    }
    __syncthreads();
  }
  const int quad = lane >> 4;
#pragma unroll
  for (int ni = 0; ni < 2; ni++) {
    const int col = n0 + wn * 32 + ni * 16 + lane_m;
    const float bv = bf2f(bias[col]);
#pragma unroll
    for (int mi = 0; mi < 4; mi++) {
      const int row = m0 + wm * 64 + mi * 16 + quad * 4;
      if (wf32) {
        float* pc = (float*)Cout + (size_t)row * ldc + col;
#pragma unroll
        for (int r = 0; r < 4; r++)
          pc[(size_t)r * ldc] = acc[mi][ni][r] + bv;
      } else {
        u16* pc = (u16*)Cout + (size_t)row * ldc + col;
#pragma unroll
        for (int r = 0; r < 4; r++)
          pc[(size_t)r * ldc] = f2bf(acc[mi][ni][r] + bv);
      }
    }
  }
}

// ---- flash attention: grid (16, 32); 8 waves, 128 q-rows/block, 64-key tiles ----
// Verified r5-r9 structure. r11: rope-Q still folded in (no Qb rope pass), but
// via the precomputed table — 8 cached float2 loads replace 8 sincosf+exp2f
// (r10's +12us VALU cost). Values identical to sincosf -> bit-identical output.
__global__ __launch_bounds__(512, 4) void flash_attn(const u16* __restrict__ Q,
                                                     const u16* __restrict__ KV,
                                                     const u16* __restrict__ Vt,
                                                     const float* __restrict__ rt,
                                                     u16* __restrict__ Ctx) {
  __shared__ __align__(16) u16 lKc[64 * LKC];
  __shared__ __align__(16) u16 lKr[64 * LKR];
  __shared__ __align__(16) u16 lVt[128 * LVT];
  __shared__ __align__(16) u16 lP[8 * 16 * LP];
  const int t = threadIdx.x, lane = t & 63, w = t >> 6;
  const int col = blockIdx.y;
  const int qtile = (col < 16) ? (15 - (int)blockIdx.x) : (int)blockIdx.x;
  const int h = col & (NH - 1);
  const int b = col >> 4;
  const int q0 = qtile * 128;
  const int nkt = 2 * qtile + 2;
  const int lane_m = lane & 15, quad = lane >> 4, lane_k = quad * 8;

  // Q fragments (A-operand), one 16-row stripe per wave
  const int qrow = q0 + 16 * w + lane_m;
  const u16* qcp = Q + (size_t)(b * SQ + qrow) * LDQ + h * HD;
  const u16* qrp = Q + (size_t)(b * SQ + qrow) * LDQ + 2048 + h * RD;
  short8 qfc[4], qfr[2];
#pragma unroll
  for (int ks = 0; ks < 4; ks++) qfc[ks] = *(const short8*)(qcp + ks * 32 + lane_k);
  {
#pragma unroll
    for (int ks = 0; ks < 2; ks++) {
      short8 v = *(const short8*)(qrp + ks * 32 + lane_k);
#pragma unroll
      for (int p = 0; p < 4; p++) {
        const int j = ks * 16 + quad * 4 + p;  // rope pair index in [0,32)
        const float2 t2 = *(const float2*)(rt + ((size_t)qrow * 32 + j) * 2);
        const float x1 = bf2f((u16)v[2 * p]), x2 = bf2f((u16)v[2 * p + 1]);
        v[2 * p]     = (short)f2bf(x1 * t2.x - x2 * t2.y);
        v[2 * p + 1] = (short)f2bf(x1 * t2.y + x2 * t2.x);
      }
      qfr[ks] = v;
    }
  }

  floatx4 O[8] = {};
  float mrow[4], lsum[4];
#pragma unroll
  for (int r = 0; r < 4; r++) { mrow[r] = -1e30f; lsum[r] = 0.f; }

  const u16* gKc = KV + (size_t)b * SQ * LDKV + h * HD;          // + key*LDKV + d
  const u16* gKr = KV + (size_t)b * SQ * LDKV + 4096 + h * RD;   // + key*LDKV + d
  const u16* gVt = Vt + (size_t)(b * NH + h) * HD * SQ;          // + d*SQ + key
  const float C2 = 0.10412825525540364f;  // (1/sqrt(192)) * log2(e)
  const float THR = 28.8f;                // defer-max threshold: exp2(THR*C2)=8

  // register staging (global -> reg prefetch -> LDS), 512 threads
  short8 rKc[2], rKr, rVt[2];
  auto load_tile = [&](int kb) {
#pragma unroll
    for (int i = 0; i < 2; i++) {
      const int c = t + i * 512, row = c >> 4, cc = (c & 15) * 8;
      rKc[i] = *(const short8*)(gKc + (size_t)(kb + row) * LDKV + cc);
    }
    {
      const int row = t >> 3, cc = (t & 7) * 8;
      rKr = *(const short8*)(gKr + (size_t)(kb + row) * LDKV + cc);
    }
#pragma unroll
    for (int i = 0; i < 2; i++) {
      const int c = t + i * 512, row = c >> 3, cc = (c & 7) * 8;
      rVt[i] = *(const short8*)(gVt + (size_t)row * SQ + kb + cc);
    }
  };

  const int wrow_lo = q0 + 16 * w;
  const int wrow_hi = wrow_lo + 15;

  load_tile(0);
  for (int kt = 0; kt < nkt; kt++) {
    const int kb = kt * 64;
    __syncthreads();  // previous tile's LDS reads complete
#pragma unroll
    for (int i = 0; i < 2; i++) {
      const int c = t + i * 512, row = c >> 4, cc = (c & 15) * 8;
      *(short8*)(lKc + row * LKC + cc) = rKc[i];
    }
    {
      const int row = t >> 3, cc = (t & 7) * 8;
      *(short8*)(lKr + row * LKR + cc) = rKr;
    }
#pragma unroll
    for (int i = 0; i < 2; i++) {
      const int c = t + i * 512, row = c >> 3, cc = (c & 7) * 8;
      *(short8*)(lVt + row * LVT + cc) = rVt[i];
    }
    __syncthreads();
    if (kt < nkt - 1) load_tile(kb + 64);  // prefetch overlaps compute below

    if (kb <= wrow_hi) {  // wave-level skip of fully-masked tiles (barriers stay uniform)
      float ss[4][4];
      __builtin_amdgcn_s_setprio(1);
#pragma unroll
      for (int n = 0; n < 4; n++) {
        floatx4 a = {0.f, 0.f, 0.f, 0.f};
#pragma unroll
        for (int ks = 0; ks < 4; ks++) {
          const short8 kf = *(const short8*)(lKc + (n * 16 + lane_m) * LKC + ks * 32 + lane_k);
          a = __builtin_amdgcn_mfma_f32_16x16x32_bf16(qfc[ks], kf, a, 0, 0, 0);
        }
#pragma unroll
        for (int ks = 0; ks < 2; ks++) {
          const short8 kf = *(const short8*)(lKr + (n * 16 + lane_m) * LKR + ks * 32 + lane_k);
          a = __builtin_amdgcn_mfma_f32_16x16x32_bf16(qfr[ks], kf, a, 0, 0, 0);
        }
#pragma unroll
        for (int r = 0; r < 4; r++) ss[n][r] = a[r];
      }
      __builtin_amdgcn_s_setprio(0);
      if (kb + 63 > wrow_lo) {  // causal mask (partial tiles)
#pragma unroll
        for (int n = 0; n < 4; n++) {
          const int kcol = kb + n * 16 + lane_m;
#pragma unroll
          for (int r = 0; r < 4; r++) {
            const int row = wrow_lo + quad * 4 + r;
            if (kcol > row) ss[n][r] = -1e30f;
          }
        }
      }
      // per-row tile max
      float mt[4];
#pragma unroll
      for (int r = 0; r < 4; r++) {
        float m = fmaxf(fmaxf(ss[0][r], ss[1][r]), fmaxf(ss[2][r], ss[3][r]));
#pragma unroll
        for (int d = 1; d < 16; d <<= 1) m = fmaxf(m, __shfl_xor(m, d));
        mt[r] = m;
      }
      // T13 defer-max: rescale only if some row grew past THR
      const bool grow = (mt[0] > mrow[0] + THR) || (mt[1] > mrow[1] + THR) ||
                        (mt[2] > mrow[2] + THR) || (mt[3] > mrow[3] + THR);
      if (__any(grow)) {
#pragma unroll
        for (int r = 0; r < 4; r++) {
          const float mn = fmaxf(mrow[r], mt[r]);
          const float alpha = exp2f((mrow[r] - mn) * C2);
          mrow[r] = mn;
          lsum[r] *= alpha;
#pragma unroll
          for (int vb = 0; vb < 8; vb++) O[vb][r] *= alpha;
        }
      }
      float pw[4][4];
#pragma unroll
      for (int r = 0; r < 4; r++) {
        float s = 0.f;
#pragma unroll
        for (int n = 0; n < 4; n++) {
          const float p = exp2f((ss[n][r] - mrow[r]) * C2);
          pw[n][r] = p;
          s += p;
        }
#pragma unroll
        for (int d = 1; d < 16; d <<= 1) s += __shfl_xor(s, d);
        lsum[r] += s;
      }
      // P: C-layout -> LDS (per-wave region) -> A-layout
#pragma unroll
      for (int n = 0; n < 4; n++)
#pragma unroll
        for (int r = 0; r < 4; r++)
          lP[(w * 16 + quad * 4 + r) * LP + n * 16 + lane_m] = f2bf(pw[n][r]);
      asm volatile("s_waitcnt lgkmcnt(0)" ::: "memory");
      __builtin_amdgcn_s_setprio(1);
#pragma unroll
      for (int ks = 0; ks < 2; ks++) {
        const short8 pf = *(const short8*)(lP + (w * 16 + lane_m) * LP + ks * 32 + lane_k);
#pragma unroll
        for (int vb = 0; vb < 8; vb++) {
          const short8 vf = *(const short8*)(lVt + (vb * 16 + lane_m) * LVT + ks * 32 + lane_k);
          O[vb] = __builtin_amdgcn_mfma_f32_16x16x32_bf16(pf, vf, O[vb], 0, 0, 0);
        }
      }
      __builtin_amdgcn_s_setprio(0);
    }
  }
  float inv[4];
#pragma unroll
  for (int r = 0; r < 4; r++) inv[r] = 1.f / lsum[r];
#pragma unroll
  for (int vb = 0; vb < 8; vb++) {
#pragma unroll
    for (int r = 0; r < 4; r++) {
      const int row = wrow_lo + quad * 4 + r;
      Ctx[(size_t)(b * SQ + row) * 2048 + h * HD + vb * 16 + lane_m] = f2bf(O[vb][r] * inv[r]);
    }
  }
}

extern "C" void kernel_launch(void* const* d_in, const int* in_sizes, int n_in,
                              void* d_out, int out_size, void* d_ws, size_t ws_size,
                              hipStream_t stream) {
  (void)in_sizes; (void)n_in; (void)out_size; (void)ws_size;
  const float* x    = (const float*)d_in[0];
  const float* kvdw = (const float*)d_in[2];
  const float* kvdb = (const float*)d_in[3];
  const float* kuw  = (const float*)d_in[4];
  const float* kub  = (const float*)d_in[5];
  const float* vuw  = (const float*)d_in[6];
  const float* vub  = (const float*)d_in[7];
  const float* krw  = (const float*)d_in[8];
  const float* krb  = (const float*)d_in[9];
  const float* qdw  = (const float*)d_in[10];
  const float* qdb  = (const float*)d_in[11];
  const float* quw  = (const float*)d_in[12];
  const float* qub  = (const float*)d_in[13];
  const float* qrw  = (const float*)d_in[14];
  const float* qrb  = (const float*)d_in[15];
  const float* ow   = (const float*)d_in[16];
  const float* ob   = (const float*)d_in[17];

  // workspace layout (u16 units), ~116 MB, lifetime-aliased (see OFF_* macros)
  u16* ws   = (u16*)d_ws;
  u16* bc   = ws + OFF_BC;
  u16* WT1  = ws + OFF_WT1;
  u16* WT2  = ws + OFF_WT2;
  u16* WT3  = ws + OFF_WT3;
  u16* WTo  = ws + OFF_WTO;
  u16* KVQd = ws + OFF_KVQD;
  u16* KV   = ws + OFF_KV;
  u16* Qb   = ws + OFF_QB;
  const float* rt = (const float*)(ws + OFF_ROPE);
  u16* Ctx  = WT1;    // overlays WT1..WT3 (dead by flash)
  u16* Vt   = KVQd;   // overlays (dead after G3)
  u16* xc   = Qb;     // overlays Q (dead after G1)
  const u16* nu = (const u16*)nullptr;

  // one prep launch: convert_x + biases + 8 weight transposes + rope table
  prep<<<dim3(23856), 256, 0, stream>>>(x, kvdb, qdb, kub, vub, krb, qub, qrb, ob,
                                        kvdw, qdw, kuw, vuw, krw, quw, qrw, ow, ws);

  // G1: kv_c | q_c   (512 blocks, single param set)
  gemm_bt<<<dim3(512), 512, 0, stream>>>(1 << 30,
      xc, 2048, WT1, bc, KVQd, 2048, 0, 2048, 2048,
      nu, 0, nu, nu, (void*)nullptr, 0, 0, 0, 64);

  // G2+G3 fused: G2 = Kc|V|Kr (1280 blocks, ids 0..1279), G3 = Qc|Qr (768)
  gemm_bt<<<dim3(2048), 512, 0, stream>>>(1280,
      KVQd, 2048, WT2, bc + 2048, KV, LDKV, 0, 5120, 512,
      KVQd + 512, 2048, WT3, bc + 7168, Qb, LDQ, 0, 3072, 1536);

  // one post launch: rope(KV) via table + transpose_v
  post<<<dim3(16384), 256, 0, stream>>>(ws);

  flash_attn<<<dim3(16, 32), 512, 0, stream>>>(Qb, KV, Vt, rt, Ctx);

  // G4: out proj (f32 out)
  gemm_bt<<<dim3(512), 512, 0, stream>>>(1 << 30,
      Ctx, 2048, WTo, bc + 10240, d_out, 2048, 1, 2048, 2048,
      nu, 0, nu, nu, (void*)nullptr, 0, 0, 0, 64);
}